// Round 5
// baseline (509.865 us; speedup 1.0000x reference)
//
#include <hip/hip_runtime.h>

#define NTOK 1024
#define CDIM 1024
#define CRDIM 256
#define ENUM 8
#define IDIM 4096
#define WSTRIDE 4194304ull  // C*I elements per expert weight matrix
#define SBPAD 56            // fallback LDS row stride in ushorts

typedef __bf16 bf16x8 __attribute__((ext_vector_type(8)));
typedef float f32x4 __attribute__((ext_vector_type(4)));

typedef const unsigned int __attribute__((address_space(1))) gu32;
typedef unsigned int __attribute__((address_space(3))) lu32;

__device__ __forceinline__ void glds16(const unsigned short* g, unsigned short* l) {
  __builtin_amdgcn_global_load_lds((gu32*)g, (lu32*)l, 16, 0, 0);
}

__device__ __forceinline__ unsigned short f2bf(float f) {
  union { float f; unsigned int u; } v; v.f = f;
  unsigned int r = v.u + 0x7FFFu + ((v.u >> 16) & 1u);  // RNE
  return (unsigned short)(r >> 16);
}

// ================= device building blocks =================

__device__ __forceinline__ void init_block(int b, const float* __restrict__ x,
                                           unsigned short* __restrict__ xb,
                                           float* __restrict__ out) {
  int t = b * 256 + threadIdx.x;
  float4 v = reinterpret_cast<const float4*>(x)[t];
  ushort4 o;
  o.x = f2bf(v.x); o.y = f2bf(v.y); o.z = f2bf(v.z); o.w = f2bf(v.w);
  reinterpret_cast<ushort4*>(xb)[t] = o;
  float4 z; z.x = 0.f; z.y = 0.f; z.z = 0.f; z.w = 0.f;
  reinterpret_cast<float4*>(out)[t] = z;
}

// ---- router block: RT tokens -> top2 indices + renormalized gates ----
// x read via uniform (broadcast, L1-hit) loads; no LDS x-stage.
#define RT 8
__device__ __forceinline__ void router_block(
    int rb, const float* __restrict__ x, const float* __restrict__ Wr1,
    const float* __restrict__ br1, const float* __restrict__ Wr2,
    const float* __restrict__ br2, int* __restrict__ ti, float* __restrict__ tw,
    char* pool) {
  float (*hs)[CRDIM] = (float(*)[CRDIM])pool;            // 8 KB
  float (*lg)[ENUM] = (float(*)[ENUM])(pool + 8192);     // 256 B
  const int tid = threadIdx.x;
  const int tok0 = rb * RT;
  float acc[RT];
#pragma unroll
  for (int r = 0; r < RT; ++r) acc[r] = 0.f;
  const int j = tid;
  const float* xrow = x + (size_t)tok0 * CDIM;
  for (int i = 0; i < CDIM; ++i) {
    float w = Wr1[(size_t)i * CRDIM + j];
#pragma unroll
    for (int r = 0; r < RT; ++r) acc[r] += xrow[r * CDIM + i] * w;
  }
  float b = br1[j];
#pragma unroll
  for (int r = 0; r < RT; ++r) hs[r][j] = fmaxf(acc[r] + b, 0.f);
  __syncthreads();
  if (tid < RT * ENUM) {
    int r = tid >> 3, e = tid & 7;
    float a = 0.f;
    for (int i = 0; i < CRDIM; ++i) a += hs[r][i] * Wr2[(size_t)i * ENUM + e];
    lg[r][e] = a + br2[e];
  }
  __syncthreads();
  if (tid < RT) {
    int r = tid;
    float m = lg[r][0];
#pragma unroll
    for (int e = 1; e < 8; ++e) m = fmaxf(m, lg[r][e]);
    float s = 0.f, g[8];
#pragma unroll
    for (int e = 0; e < 8; ++e) { g[e] = expf(lg[r][e] - m); s += g[e]; }
    float inv = 1.f / s;
    int i0 = 0; float g0 = -1.f;
#pragma unroll
    for (int e = 0; e < 8; ++e) { float ge = g[e] * inv; if (ge > g0) { g0 = ge; i0 = e; } }
    int i1 = 0; float g1 = -2.f;
#pragma unroll
    for (int e = 0; e < 8; ++e) { float ge = g[e] * inv; if (e != i0 && ge > g1) { g1 = ge; i1 = e; } }
    float w0 = 1.f / (1.f + expf((g1 - g0) * 0.5f));
    int n = tok0 + r;
    ti[2 * n] = i0; ti[2 * n + 1] = i1;
    tw[2 * n] = w0; tw[2 * n + 1] = 1.f - w0;
  }
}

// ---- transpose + f32->bf16: src [KD][ND] tile -> dst [ND][KD] ----
template <int KD, int ND>
__device__ __forceinline__ void transpose_block(
    const float* __restrict__ src, unsigned short* __restrict__ dse,
    int n0, int k0, unsigned short* lt /* 128*136 ushorts */) {
  const int tid = threadIdx.x;
  const int bn = tid >> 3, bk0 = tid & 7;
#pragma unroll
  for (int i = 0; i < 4; ++i) {
    const int bk = bk0 + 8 * i;
    const float* sp = src + (size_t)(k0 + 4 * bk) * ND + n0 + 4 * bn;
    float4 r0 = *reinterpret_cast<const float4*>(sp);
    float4 r1 = *reinterpret_cast<const float4*>(sp + ND);
    float4 r2 = *reinterpret_cast<const float4*>(sp + 2 * (size_t)ND);
    float4 r3 = *reinterpret_cast<const float4*>(sp + 3 * (size_t)ND);
    ushort4 c;
    c.x = f2bf(r0.x); c.y = f2bf(r1.x); c.z = f2bf(r2.x); c.w = f2bf(r3.x);
    *reinterpret_cast<ushort4*>(&lt[(4 * bn + 0) * 136 + 4 * bk]) = c;
    c.x = f2bf(r0.y); c.y = f2bf(r1.y); c.z = f2bf(r2.y); c.w = f2bf(r3.y);
    *reinterpret_cast<ushort4*>(&lt[(4 * bn + 1) * 136 + 4 * bk]) = c;
    c.x = f2bf(r0.z); c.y = f2bf(r1.z); c.z = f2bf(r2.z); c.w = f2bf(r3.z);
    *reinterpret_cast<ushort4*>(&lt[(4 * bn + 2) * 136 + 4 * bk]) = c;
    c.x = f2bf(r0.w); c.y = f2bf(r1.w); c.z = f2bf(r2.w); c.w = f2bf(r3.w);
    *reinterpret_cast<ushort4*>(&lt[(4 * bn + 3) * 136 + 4 * bk]) = c;
  }
  __syncthreads();
#pragma unroll
  for (int p = 0; p < 2; ++p) {
    const int n = (tid >> 2) + 64 * p;
    const int seg = (tid & 3) * 32;
    const uint4 d0 = *reinterpret_cast<const uint4*>(&lt[n * 136 + seg]);
    const uint4 d1 = *reinterpret_cast<const uint4*>(&lt[n * 136 + seg + 8]);
    const uint4 d2 = *reinterpret_cast<const uint4*>(&lt[n * 136 + seg + 16]);
    const uint4 d3 = *reinterpret_cast<const uint4*>(&lt[n * 136 + seg + 24]);
    unsigned short* o = dse + (size_t)(n0 + n) * KD + k0 + seg;
    reinterpret_cast<uint4*>(o)[0] = d0;
    reinterpret_cast<uint4*>(o)[1] = d1;
    reinterpret_cast<uint4*>(o)[2] = d2;
    reinterpret_cast<uint4*>(o)[3] = d3;
  }
}

// ---- 2-phase double-buffered MFMA GEMM block (T3-min recipe) ----
// MODE 0: H = silu(Xg @ W1T^T + b1); MODE 1: out += gate*(H @ W2T^T + b2), split-K=4
template <int MODE>
__device__ __forceinline__ void gemm_block(
    const unsigned short* __restrict__ Abase, const unsigned short* __restrict__ Bt,
    const float* __restrict__ br, const float* __restrict__ bsh,
    const int* __restrict__ cnt, const int* __restrict__ offs,
    const int* __restrict__ list, const float* __restrict__ gw,
    unsigned short* __restrict__ Hout, float* __restrict__ out,
    int mt, int nt, int zz, unsigned short* sm /* 16384 ushorts */,
    int* sTok, float* sGate) {
  constexpr int KD = (MODE == 0) ? CDIM : IDIM;
  constexpr int ND = (MODE == 0) ? IDIM : CDIM;
  constexpr int KCH = (MODE == 0) ? KD : (KD / 4);
  constexpr int NT = KCH / 32;
  const int e = (MODE == 0) ? zz : (zz % 9);
  const int kc = (MODE == 0) ? 0 : (zz / 9);
  const int me = (e < 8) ? cnt[e] : NTOK;
  const int row0 = mt * 128;
  if (row0 >= me) return;
  const int valid = min(128, me - row0);
  const int n0 = nt * 128;
  const unsigned short* Bsrc = Bt + (size_t)e * WSTRIDE;
  const float* bias = (e < 8) ? (br + (size_t)e * ND) : bsh;
  const int hbase = (e < 8) ? offs[e] : 2048;
  const int tid = threadIdx.x;
  const int lane = tid & 63, w = tid >> 6;

  if (MODE == 1 && e < 8 && tid < 128) {
    int ic = min(tid, valid - 1);
    sTok[tid] = list[e * NTOK + row0 + ic];
    sGate[tid] = (tid < valid) ? gw[e * NTOK + row0 + tid] : 0.f;
  }

  // staging: wave w covers rows [16w,16w+16) and [64+16w,..); swizzled k-chunks
  const int rl = lane >> 2, cs = lane & 3;
  const int ra0 = w * 16 + rl, ra1 = 64 + w * 16 + rl;
  const int qa0 = cs ^ ((ra0 >> 1) & 3), qa1 = cs ^ ((ra1 >> 1) & 3);
  const int kbeg = kc * KCH;
  size_t arow0, arow1;
  if (MODE == 0) {
    if (e < 8) {
      arow0 = (size_t)list[e * NTOK + row0 + min(ra0, valid - 1)];
      arow1 = (size_t)list[e * NTOK + row0 + min(ra1, valid - 1)];
    } else { arow0 = (size_t)(row0 + ra0); arow1 = (size_t)(row0 + ra1); }
  } else { arow0 = (size_t)(hbase + row0 + ra0); arow1 = (size_t)(hbase + row0 + ra1); }
  const unsigned short* srcA0 = Abase + arow0 * KD + kbeg + qa0 * 8;
  const unsigned short* srcA1 = Abase + arow1 * KD + kbeg + qa1 * 8;
  const unsigned short* srcB0 = Bsrc + (size_t)(n0 + ra0) * KD + kbeg + qa0 * 8;
  const unsigned short* srcB1 = Bsrc + (size_t)(n0 + ra1) * KD + kbeg + qa1 * 8;
  const int aO0 = (w * 16) * 32;
  const int aO1 = (64 + w * 16) * 32;

  const int wr = (w >> 1) * 64, wc = (w & 1) * 64;
  const int lr = lane & 15, q = lane >> 4;
  int offA[4], offB[4];
#pragma unroll
  for (int m = 0; m < 4; ++m) { int R = wr + m * 16 + lr; offA[m] = R * 32 + (q ^ ((R >> 1) & 3)) * 8; }
#pragma unroll
  for (int n = 0; n < 4; ++n) { int R = wc + n * 16 + lr; offB[n] = R * 32 + (q ^ ((R >> 1) & 3)) * 8; }

  f32x4 acc[4][4];
#pragma unroll
  for (int m = 0; m < 4; ++m)
#pragma unroll
    for (int n = 0; n < 4; ++n) acc[m][n] = (f32x4)0.f;

  // sm layout (ushorts): A bufs [0,8192), B bufs [8192,16384)
#define STG(T, BUF)                                              \
  {                                                              \
    const int ko = (T) * 32;                                     \
    glds16(srcA0 + ko, sm + (BUF) * 4096 + aO0);                 \
    glds16(srcA1 + ko, sm + (BUF) * 4096 + aO1);                 \
    glds16(srcB0 + ko, sm + 8192 + (BUF) * 4096 + aO0);          \
    glds16(srcB1 + ko, sm + 8192 + (BUF) * 4096 + aO1);          \
  }

  // prologue: stage tile 0, drain, publish
  STG(0, 0);
  asm volatile("s_waitcnt vmcnt(0)" ::: "memory");
  __builtin_amdgcn_s_barrier();

#pragma unroll 2
  for (int t = 0; t < NT; ++t) {
    const int cur = t & 1;
    if (t + 1 < NT) STG(t + 1, cur ^ 1);  // prefetch overlaps this iter's compute
    const unsigned short* pA = sm + cur * 4096;
    const unsigned short* pB = sm + 8192 + cur * 4096;
    bf16x8 av[4], bv[4];
#pragma unroll
    for (int m = 0; m < 4; ++m) av[m] = *reinterpret_cast<const bf16x8*>(pA + offA[m]);
#pragma unroll
    for (int n = 0; n < 4; ++n) bv[n] = *reinterpret_cast<const bf16x8*>(pB + offB[n]);
#pragma unroll
    for (int m = 0; m < 4; ++m)
#pragma unroll
      for (int n = 0; n < 4; ++n)
        acc[m][n] = __builtin_amdgcn_mfma_f32_16x16x32_bf16(av[m], bv[n], acc[m][n], 0, 0, 0);
    asm volatile("s_waitcnt vmcnt(0)" ::: "memory");  // next tile resident (per-wave)
    __builtin_amdgcn_s_barrier();                     // publish to all waves
  }
#undef STG

  const int rbase = wr + (q << 2);
#pragma unroll
  for (int n = 0; n < 4; ++n) {
    const int col = n0 + wc + n * 16 + lr;
    const float bval = (MODE == 0 || kc == 0) ? bias[col] : 0.f;
#pragma unroll
    for (int m = 0; m < 4; ++m) {
#pragma unroll
      for (int r = 0; r < 4; ++r) {
        const int i = rbase + m * 16 + r;
        if (i < valid) {
          float v = acc[m][n][r] + bval;
          if (MODE == 0) {
            float sv = v / (1.f + __expf(-v));
            Hout[(size_t)(hbase + row0 + i) * IDIM + col] = f2bf(sv);
          } else {
            if (e < 8)
              atomicAdd(&out[(size_t)sTok[i] * CDIM + col], sGate[i] * v);
            else
              atomicAdd(&out[(size_t)(row0 + i) * CDIM + col], v);
          }
        }
      }
    }
  }
}

// ================= kernels =================

// prep: [0,1024) init/zero; [1024,1152) router; [1152,3456) T1; [3456,5760) T2
__global__ __launch_bounds__(256) void prep_kernel(
    const float* __restrict__ x, unsigned short* __restrict__ xb,
    float* __restrict__ out, const float* __restrict__ Wr1,
    const float* __restrict__ br1, const float* __restrict__ Wr2,
    const float* __restrict__ br2, int* __restrict__ ti, float* __restrict__ tw,
    const float* __restrict__ We1, const float* __restrict__ Ws1,
    unsigned short* __restrict__ W1T, const float* __restrict__ We2,
    const float* __restrict__ Ws2, unsigned short* __restrict__ W2T) {
  __shared__ __align__(16) char pool[34816];
  const int b = blockIdx.x;
  if (b < 1024) {
    init_block(b, x, xb, out);
  } else if (b < 1152) {
    router_block(b - 1024, x, Wr1, br1, Wr2, br2, ti, tw, pool);
  } else if (b < 3456) {
    const int local = b - 1152;
    const int e = local >> 8, rem = local & 255;
    const float* src = (e < 8) ? (We1 + (size_t)e * WSTRIDE) : Ws1;
    transpose_block<CDIM, IDIM>(src, W1T + (size_t)e * WSTRIDE,
                                (rem & 31) * 128, (rem >> 5) * 128,
                                (unsigned short*)pool);
  } else {
    const int local = b - 3456;
    const int e = local >> 8, rem = local & 255;
    const float* src = (e < 8) ? (We2 + (size_t)e * WSTRIDE) : Ws2;
    transpose_block<IDIM, CDIM>(src, W2T + (size_t)e * WSTRIDE,
                                (rem & 7) * 128, (rem >> 3) * 128,
                                (unsigned short*)pool);
  }
}

__global__ __launch_bounds__(1024) void build_lists_kernel(
    const int* __restrict__ ti, const float* __restrict__ tw,
    int* __restrict__ cnt, int* __restrict__ list, float* __restrict__ gw) {
  __shared__ int s[NTOK];
  const int e = blockIdx.x, n = threadIdx.x;
  int a = ti[2 * n], b = ti[2 * n + 1];
  float w = (a == e) ? tw[2 * n] : ((b == e) ? tw[2 * n + 1] : 0.f);
  int flag = (a == e || b == e) ? 1 : 0;
  s[n] = flag;
  __syncthreads();
  for (int off = 1; off < NTOK; off <<= 1) {
    int v = (n >= off) ? s[n - off] : 0;
    __syncthreads();
    s[n] += v;
    __syncthreads();
  }
  if (flag) { int pos = s[n] - 1; list[e * NTOK + pos] = n; gw[e * NTOK + pos] = w; }
  if (n == NTOK - 1) cnt[e] = s[n];
}

__global__ void offsets_kernel(const int* __restrict__ cnt, int* __restrict__ offs) {
  if (threadIdx.x == 0) {
    int o = 0;
    for (int e = 0; e < 8; ++e) { offs[e] = o; o += cnt[e]; }
    offs[8] = o;
  }
}

__global__ __launch_bounds__(256) void gemm1_kernel(
    const unsigned short* __restrict__ xb, const unsigned short* __restrict__ W1T,
    const float* __restrict__ be1, const float* __restrict__ bs1,
    const int* __restrict__ cnt, const int* __restrict__ offs,
    const int* __restrict__ list, unsigned short* __restrict__ H) {
  __shared__ __align__(16) unsigned short sm[16384];
  gemm_block<0>(xb, W1T, be1, bs1, cnt, offs, list, nullptr, H, nullptr,
                blockIdx.x, blockIdx.y, blockIdx.z, sm, nullptr, nullptr);
}

__global__ __launch_bounds__(256) void gemm2_kernel(
    const unsigned short* __restrict__ H, const unsigned short* __restrict__ W2T,
    const float* __restrict__ be2, const float* __restrict__ bs2,
    const int* __restrict__ cnt, const int* __restrict__ offs,
    const int* __restrict__ list, const float* __restrict__ gw,
    float* __restrict__ out) {
  __shared__ __align__(16) unsigned short sm[16384];
  __shared__ int sTok[128];
  __shared__ float sGate[128];
  gemm_block<1>(H, W2T, be2, bs2, cnt, offs, list, gw, nullptr, out,
                blockIdx.x, blockIdx.y, blockIdx.z, sm, sTok, sGate);
}

// ---------------- fallback GEMM (f32 weights direct; small-ws path) ----------
template <int MODE>
__global__ __launch_bounds__(256) void moe_gemm(
    const unsigned short* __restrict__ Abase, const float* __restrict__ Wr,
    const float* __restrict__ Wsh, const float* __restrict__ br,
    const float* __restrict__ bsh, const int* __restrict__ cnt,
    const int* __restrict__ offs, const int* __restrict__ list,
    const float* __restrict__ gw, unsigned short* __restrict__ Hout,
    float* __restrict__ out) {
  constexpr int KD = (MODE == 0) ? CDIM : IDIM;
  constexpr int ND = (MODE == 0) ? IDIM : CDIM;
  constexpr int KCH = (MODE == 0) ? KD : (KD / 4);
  const int nt = blockIdx.x, mt = blockIdx.y;
  const int e = (MODE == 0) ? blockIdx.z : (blockIdx.z % 9);
  const int kc = (MODE == 0) ? 0 : (blockIdx.z / 9);
  const int me = (e < 8) ? cnt[e] : NTOK;
  const int row0 = mt * 128;
  if (row0 >= me) return;
  const int valid = min(128, me - row0);
  const int n0 = nt * 128;
  const float* Bsrc = (e < 8) ? (Wr + (size_t)e * WSTRIDE) : Wsh;
  const float* bias = (e < 8) ? (br + (size_t)e * ND) : bsh;
  const int hbase = (e < 8) ? offs[e] : 2048;
  const int tid = threadIdx.x;

  __shared__ __align__(16) unsigned short sA[128][SBPAD];
  __shared__ __align__(16) unsigned short sB[128][SBPAD];
  __shared__ int rowSrc[128];
  __shared__ int sTok[128];
  __shared__ float sGate[128];

  if (tid < 128) {
    int i = tid, ic = min(i, valid - 1);
    if (MODE == 0) {
      rowSrc[i] = (e < 8) ? list[e * NTOK + row0 + ic] : (row0 + ic);
    } else {
      rowSrc[i] = hbase + row0 + i;
      if (e < 8) {
        sTok[i] = list[e * NTOK + row0 + ic];
        sGate[i] = (i < valid) ? gw[e * NTOK + row0 + i] : 0.f;
      }
    }
  }

  f32x4 acc[4][4];
#pragma unroll
  for (int m = 0; m < 4; ++m)
#pragma unroll
    for (int n = 0; n < 4; ++n) acc[m][n] = (f32x4)0.f;

  const int lane = tid & 63;
  const int wv = tid >> 6;
  const int wr = (wv >> 1) * 64, wc = (wv & 1) * 64;
  const int lr = lane & 15, lk = (lane >> 4) * 8;
  const int rowA = tid >> 2, kgA = (tid & 3) * 8;
  const int ncB = (tid & 63) * 2, kpB = tid >> 6;
  __syncthreads();

  const int kbeg = kc * KCH, kend = kbeg + KCH;
  uint4 pa0, pa1;
  float2 pb[8];

#define LOADTILE(K0)                                                            \
  {                                                                             \
    pa0 = *reinterpret_cast<const uint4*>(Abase + (size_t)rowSrc[rowA] * KD + (K0) + kgA);      \
    pa1 = *reinterpret_cast<const uint4*>(Abase + (size_t)rowSrc[rowA + 64] * KD + (K0) + kgA); \
    const float* Bp = Bsrc + (size_t)((K0) + kpB * 8) * ND + n0 + ncB;          \
    _Pragma("unroll") for (int j = 0; j < 8; ++j)                               \
        pb[j] = *reinterpret_cast<const float2*>(Bp + (size_t)j * ND);          \
  }

  LOADTILE(kbeg);
  for (int k0 = kbeg; k0 < kend; k0 += 32) {
    __syncthreads();
    *reinterpret_cast<uint4*>(&sA[rowA][kgA]) = pa0;
    *reinterpret_cast<uint4*>(&sA[rowA + 64][kgA]) = pa1;
    {
      bf16x8 q0, q1;
#pragma unroll
      for (int j = 0; j < 8; ++j) { q0[j] = (__bf16)pb[j].x; q1[j] = (__bf16)pb[j].y; }
      *reinterpret_cast<bf16x8*>(&sB[ncB][kpB * 8]) = q0;
      *reinterpret_cast<bf16x8*>(&sB[ncB + 1][kpB * 8]) = q1;
    }
    __syncthreads();
    if (k0 + 32 < kend) LOADTILE(k0 + 32);
    bf16x8 av[4], bv[4];
#pragma unroll
    for (int m = 0; m < 4; ++m)
      av[m] = *reinterpret_cast<const bf16x8*>(&sA[wr + m * 16 + lr][lk]);
#pragma unroll
    for (int n = 0; n < 4; ++n)
      bv[n] = *reinterpret_cast<const bf16x8*>(&sB[wc + n * 16 + lr][lk]);
#pragma unroll
    for (int m = 0; m < 4; ++m)
#pragma unroll
      for (int n = 0; n < 4; ++n)
        acc[m][n] = __builtin_amdgcn_mfma_f32_16x16x32_bf16(av[m], bv[n], acc[m][n], 0, 0, 0);
  }
#undef LOADTILE

  const int rbase = wr + ((lane >> 4) << 2);
#pragma unroll
  for (int n = 0; n < 4; ++n) {
    const int col = n0 + wc + n * 16 + lr;
    const float bval = (MODE == 0 || kc == 0) ? bias[col] : 0.f;
#pragma unroll
    for (int m = 0; m < 4; ++m) {
#pragma unroll
      for (int r = 0; r < 4; ++r) {
        const int i = rbase + m * 16 + r;
        if (i < valid) {
          float v = acc[m][n][r] + bval;
          if (MODE == 0) {
            float sv = v / (1.f + __expf(-v));
            Hout[(size_t)(hbase + row0 + i) * IDIM + col] = f2bf(sv);
          } else {
            if (e < 8)
              atomicAdd(&out[(size_t)sTok[i] * CDIM + col], sGate[i] * v);
            else
              atomicAdd(&out[(size_t)(row0 + i) * CDIM + col], v);
          }
        }
      }
    }
  }
}

__global__ __launch_bounds__(256) void init_cast_kernel(
    const float* __restrict__ x, unsigned short* __restrict__ xb,
    float* __restrict__ out) {
  init_block(blockIdx.x, x, xb, out);
}

__global__ __launch_bounds__(256) void router_only_kernel(
    const float* __restrict__ x, const float* __restrict__ Wr1,
    const float* __restrict__ br1, const float* __restrict__ Wr2,
    const float* __restrict__ br2, int* __restrict__ ti, float* __restrict__ tw) {
  __shared__ __align__(16) char pool[8448];
  router_block(blockIdx.x, x, Wr1, br1, Wr2, br2, ti, tw, pool);
}

extern "C" void kernel_launch(void* const* d_in, const int* in_sizes, int n_in,
                              void* d_out, int out_size, void* d_ws, size_t ws_size,
                              hipStream_t stream) {
  const float* x = (const float*)d_in[0];
  const float* Wr1 = (const float*)d_in[1];
  const float* br1 = (const float*)d_in[2];
  const float* Wr2 = (const float*)d_in[3];
  const float* br2 = (const float*)d_in[4];
  const float* Ws1 = (const float*)d_in[5];
  const float* bs1 = (const float*)d_in[6];
  const float* Ws2 = (const float*)d_in[7];
  const float* bs2 = (const float*)d_in[8];
  const float* We1 = (const float*)d_in[9];
  const float* be1 = (const float*)d_in[10];
  const float* We2 = (const float*)d_in[11];
  const float* be2 = (const float*)d_in[12];
  float* out = (float*)d_out;

  char* ws = (char*)d_ws;
  unsigned short* xb = (unsigned short*)(ws + 0);            // 2 MB
  int* ti = (int*)(ws + 2097152);
  float* tw = (float*)(ws + 2105344);
  int* cnt = (int*)(ws + 2113536);
  int* offs = (int*)(ws + 2113792);
  int* list = (int*)(ws + 2114048);
  float* gw = (float*)(ws + 2146816);
  unsigned short* H = (unsigned short*)(ws + 2179584);       // 24 MB
  const bool huge = ws_size >= 179ull * 1024 * 1024;
  unsigned short* W1T = (unsigned short*)(ws + 27345920ull);               // 72 MB
  unsigned short* W2T = (unsigned short*)(ws + 102843904ull);              // 72 MB

  if (huge) {
    prep_kernel<<<5760, 256, 0, stream>>>(x, xb, out, Wr1, br1, Wr2, br2, ti, tw,
                                          We1, Ws1, W1T, We2, Ws2, W2T);
    build_lists_kernel<<<8, 1024, 0, stream>>>(ti, tw, cnt, list, gw);
    offsets_kernel<<<1, 64, 0, stream>>>(cnt, offs);
    gemm1_kernel<<<dim3(8, 32, 9), 256, 0, stream>>>(xb, W1T, be1, bs1, cnt, offs, list, H);
    gemm2_kernel<<<dim3(8, 8, 36), 256, 0, stream>>>(H, W2T, be2, bs2, cnt, offs,
                                                     list, gw, out);
  } else {
    init_cast_kernel<<<1024, 256, 0, stream>>>(x, xb, out);
    router_only_kernel<<<NTOK / RT, 256, 0, stream>>>(x, Wr1, br1, Wr2, br2, ti, tw);
    build_lists_kernel<<<8, 1024, 0, stream>>>(ti, tw, cnt, list, gw);
    offsets_kernel<<<1, 64, 0, stream>>>(cnt, offs);
    moe_gemm<0><<<dim3(32, 8, 9), 256, 0, stream>>>(xb, We1, Ws1, be1, bs1, cnt, offs, list, gw, H, out);
    moe_gemm<1><<<dim3(8, 8, 36), 256, 0, stream>>>(H, We2, Ws2, be2, bs2, cnt, offs, list, gw, nullptr, out);
  }
}

// Round 6
// 359.955 us; speedup vs baseline: 1.4165x; 1.4165x over previous
//
#include <hip/hip_runtime.h>

#define NTOK 1024
#define CDIM 1024
#define CRDIM 256
#define ENUM 8
#define IDIM 4096
#define WSTRIDE 4194304ull  // C*I elements per expert weight matrix
#define SBPAD 56            // fallback LDS row stride in ushorts

typedef __bf16 bf16x8 __attribute__((ext_vector_type(8)));
typedef float f32x4 __attribute__((ext_vector_type(4)));

typedef const unsigned int __attribute__((address_space(1))) gu32;
typedef unsigned int __attribute__((address_space(3))) lu32;

__device__ __forceinline__ void glds16(const unsigned short* g, unsigned short* l) {
  __builtin_amdgcn_global_load_lds((gu32*)g, (lu32*)l, 16, 0, 0);
}

__device__ __forceinline__ unsigned short f2bf(float f) {
  union { float f; unsigned int u; } v; v.f = f;
  unsigned int r = v.u + 0x7FFFu + ((v.u >> 16) & 1u);  // RNE
  return (unsigned short)(r >> 16);
}

// ---------------- init + cast x to bf16, zero out ----------------
__global__ __launch_bounds__(256) void init_cast_kernel(
    const float* __restrict__ x, unsigned short* __restrict__ xb,
    float* __restrict__ out) {
  int t = blockIdx.x * 256 + threadIdx.x;
  float4 v = reinterpret_cast<const float4*>(x)[t];
  ushort4 o;
  o.x = f2bf(v.x); o.y = f2bf(v.y); o.z = f2bf(v.z); o.w = f2bf(v.w);
  reinterpret_cast<ushort4*>(xb)[t] = o;
  float4 z; z.x = 0.f; z.y = 0.f; z.z = 0.f; z.w = 0.f;
  reinterpret_cast<float4*>(out)[t] = z;
}

// ---------------- router: gates + top-2 ----------------
#define RT 8
__global__ __launch_bounds__(256) void router_kernel(
    const float* __restrict__ x, const float* __restrict__ Wr1,
    const float* __restrict__ br1, const float* __restrict__ Wr2,
    const float* __restrict__ br2, int* __restrict__ ti,
    float* __restrict__ tw) {
  __shared__ float xs[RT][CDIM];
  __shared__ float hs[RT][CRDIM];
  __shared__ float lg[RT][ENUM];
  const int tid = threadIdx.x;
  const int tok0 = blockIdx.x * RT;
  for (int r = 0; r < RT; ++r) {
    float4 v = reinterpret_cast<const float4*>(x + (size_t)(tok0 + r) * CDIM)[tid];
    *reinterpret_cast<float4*>(&xs[r][tid * 4]) = v;
  }
  __syncthreads();
  float acc[RT];
#pragma unroll
  for (int r = 0; r < RT; ++r) acc[r] = 0.f;
  const int j = tid;
  for (int i = 0; i < CDIM; ++i) {
    float w = Wr1[(size_t)i * CRDIM + j];
#pragma unroll
    for (int r = 0; r < RT; ++r) acc[r] += xs[r][i] * w;
  }
  float b = br1[j];
#pragma unroll
  for (int r = 0; r < RT; ++r) hs[r][j] = fmaxf(acc[r] + b, 0.f);
  __syncthreads();
  if (tid < RT * ENUM) {
    int r = tid >> 3, e = tid & 7;
    float a = 0.f;
    for (int i = 0; i < CRDIM; ++i) a += hs[r][i] * Wr2[(size_t)i * ENUM + e];
    lg[r][e] = a + br2[e];
  }
  __syncthreads();
  if (tid < RT) {
    int r = tid;
    float m = lg[r][0];
#pragma unroll
    for (int e = 1; e < 8; ++e) m = fmaxf(m, lg[r][e]);
    float s = 0.f, g[8];
#pragma unroll
    for (int e = 0; e < 8; ++e) { g[e] = expf(lg[r][e] - m); s += g[e]; }
    float inv = 1.f / s;
    int i0 = 0; float g0 = -1.f;
#pragma unroll
    for (int e = 0; e < 8; ++e) { float ge = g[e] * inv; if (ge > g0) { g0 = ge; i0 = e; } }
    int i1 = 0; float g1 = -2.f;
#pragma unroll
    for (int e = 0; e < 8; ++e) { float ge = g[e] * inv; if (e != i0 && ge > g1) { g1 = ge; i1 = e; } }
    float w0 = 1.f / (1.f + expf((g1 - g0) * 0.5f));
    int n = tok0 + r;
    ti[2 * n] = i0; ti[2 * n + 1] = i1;
    tw[2 * n] = w0; tw[2 * n + 1] = 1.f - w0;
  }
}

// ---------------- per-expert token lists (stable order) ----------------
__global__ __launch_bounds__(1024) void build_lists_kernel(
    const int* __restrict__ ti, const float* __restrict__ tw,
    int* __restrict__ cnt, int* __restrict__ list, float* __restrict__ gw) {
  __shared__ int s[NTOK];
  const int e = blockIdx.x, n = threadIdx.x;
  int a = ti[2 * n], b = ti[2 * n + 1];
  float w = (a == e) ? tw[2 * n] : ((b == e) ? tw[2 * n + 1] : 0.f);
  int flag = (a == e || b == e) ? 1 : 0;
  s[n] = flag;
  __syncthreads();
  for (int off = 1; off < NTOK; off <<= 1) {
    int v = (n >= off) ? s[n - off] : 0;
    __syncthreads();
    s[n] += v;
    __syncthreads();
  }
  if (flag) { int pos = s[n] - 1; list[e * NTOK + pos] = n; gw[e * NTOK + pos] = w; }
  if (n == NTOK - 1) cnt[e] = s[n];
}

// offsets + M-tile table: tbl[0]=ntt; tbl[1+i]=expert; tbl[41+i]=row0
__global__ void offsets_kernel(const int* __restrict__ cnt, int* __restrict__ offs,
                               int* __restrict__ tbl) {
  if (threadIdx.x == 0) {
    int o = 0;
    for (int e = 0; e < 8; ++e) { offs[e] = o; o += cnt[e]; }
    offs[8] = o;
    int k = 0;
    for (int e = 0; e < 9; ++e) {
      int me = (e < 8) ? cnt[e] : NTOK;
      for (int r0 = 0; r0 < me; r0 += 128) { tbl[1 + k] = e; tbl[41 + k] = r0; ++k; }
    }
    tbl[0] = k;
  }
}

// ---------------- transpose + f32->bf16 convert: src [KD][ND] -> dst [ND][KD] ----
template <int KD, int ND>
__global__ __launch_bounds__(256) void transpose_cvt(
    const float* __restrict__ Wr, const float* __restrict__ Wsh,
    unsigned short* __restrict__ dst) {
  const int e = blockIdx.z;
  const float* src = (e < 8) ? (Wr + (size_t)e * WSTRIDE) : Wsh;
  unsigned short* dse = dst + (size_t)e * WSTRIDE;
  const int n0 = blockIdx.x * 128, k0 = blockIdx.y * 128;
  __shared__ __align__(16) unsigned short lt[128][136];
  const int tid = threadIdx.x;
  const int bn = tid >> 3, bk0 = tid & 7;
#pragma unroll
  for (int i = 0; i < 4; ++i) {
    const int bk = bk0 + 8 * i;
    const float* sp = src + (size_t)(k0 + 4 * bk) * ND + n0 + 4 * bn;
    float4 r0 = *reinterpret_cast<const float4*>(sp);
    float4 r1 = *reinterpret_cast<const float4*>(sp + ND);
    float4 r2 = *reinterpret_cast<const float4*>(sp + 2 * (size_t)ND);
    float4 r3 = *reinterpret_cast<const float4*>(sp + 3 * (size_t)ND);
    ushort4 c;
    c.x = f2bf(r0.x); c.y = f2bf(r1.x); c.z = f2bf(r2.x); c.w = f2bf(r3.x);
    *reinterpret_cast<ushort4*>(&lt[4 * bn + 0][4 * bk]) = c;
    c.x = f2bf(r0.y); c.y = f2bf(r1.y); c.z = f2bf(r2.y); c.w = f2bf(r3.y);
    *reinterpret_cast<ushort4*>(&lt[4 * bn + 1][4 * bk]) = c;
    c.x = f2bf(r0.z); c.y = f2bf(r1.z); c.z = f2bf(r2.z); c.w = f2bf(r3.z);
    *reinterpret_cast<ushort4*>(&lt[4 * bn + 2][4 * bk]) = c;
    c.x = f2bf(r0.w); c.y = f2bf(r1.w); c.z = f2bf(r2.w); c.w = f2bf(r3.w);
    *reinterpret_cast<ushort4*>(&lt[4 * bn + 3][4 * bk]) = c;
  }
  __syncthreads();
#pragma unroll
  for (int p = 0; p < 2; ++p) {
    const int n = (tid >> 2) + 64 * p;
    const int seg = (tid & 3) * 32;
    const uint4 d0 = *reinterpret_cast<const uint4*>(&lt[n][seg]);
    const uint4 d1 = *reinterpret_cast<const uint4*>(&lt[n][seg + 8]);
    const uint4 d2 = *reinterpret_cast<const uint4*>(&lt[n][seg + 16]);
    const uint4 d3 = *reinterpret_cast<const uint4*>(&lt[n][seg + 24]);
    unsigned short* o = dse + (size_t)(n0 + n) * KD + k0 + seg;
    reinterpret_cast<uint4*>(o)[0] = d0;
    reinterpret_cast<uint4*>(o)[1] = d1;
    reinterpret_cast<uint4*>(o)[2] = d2;
    reinterpret_cast<uint4*>(o)[3] = d3;
  }
}

// ---- 3-buffer pipelined MFMA GEMM block (counted vmcnt, never drain-0 in loop) ----
// MODE 0: H = silu(Xg @ W1T^T + b1); MODE 1: out += gate*(H @ W2T^T + b2), split-K=4
template <int MODE>
__device__ __forceinline__ void gemm_block(
    const unsigned short* __restrict__ Abase, const unsigned short* __restrict__ Bt,
    const float* __restrict__ br, const float* __restrict__ bsh,
    const int* __restrict__ cnt, const int* __restrict__ offs,
    const int* __restrict__ list, const float* __restrict__ gw,
    unsigned short* __restrict__ Hout, float* __restrict__ out,
    int e, int row0, int kc, int nt, unsigned short* sm /* 24576 ushorts */,
    int* sTok, float* sGate) {
  constexpr int KD = (MODE == 0) ? CDIM : IDIM;
  constexpr int ND = (MODE == 0) ? IDIM : CDIM;
  constexpr int KCH = (MODE == 0) ? KD : (KD / 4);
  constexpr int NT = KCH / 32;
  const int me = (e < 8) ? cnt[e] : NTOK;
  const int valid = min(128, me - row0);
  const int n0 = nt * 128;
  const unsigned short* Bsrc = Bt + (size_t)e * WSTRIDE;
  const float* bias = (e < 8) ? (br + (size_t)e * ND) : bsh;
  const int hbase = (e < 8) ? offs[e] : 2048;
  const int tid = threadIdx.x;
  const int lane = tid & 63, w = tid >> 6;

  if (MODE == 1 && e < 8 && tid < 128) {
    int ic = min(tid, valid - 1);
    sTok[tid] = list[e * NTOK + row0 + ic];
    sGate[tid] = (tid < valid) ? gw[e * NTOK + row0 + tid] : 0.f;
  }

  // staging: wave w covers rows [16w,16w+16) and [64+16w,..); swizzled k-chunks
  const int rl = lane >> 2, cs = lane & 3;
  const int ra0 = w * 16 + rl, ra1 = 64 + w * 16 + rl;
  const int qa0 = cs ^ ((ra0 >> 1) & 3), qa1 = cs ^ ((ra1 >> 1) & 3);
  const int kbeg = kc * KCH;
  size_t arow0, arow1;
  if (MODE == 0) {
    if (e < 8) {
      arow0 = (size_t)list[e * NTOK + row0 + min(ra0, valid - 1)];
      arow1 = (size_t)list[e * NTOK + row0 + min(ra1, valid - 1)];
    } else { arow0 = (size_t)(row0 + ra0); arow1 = (size_t)(row0 + ra1); }
  } else { arow0 = (size_t)(hbase + row0 + ra0); arow1 = (size_t)(hbase + row0 + ra1); }
  const unsigned short* srcA0 = Abase + arow0 * KD + kbeg + qa0 * 8;
  const unsigned short* srcA1 = Abase + arow1 * KD + kbeg + qa1 * 8;
  const unsigned short* srcB0 = Bsrc + (size_t)(n0 + ra0) * KD + kbeg + qa0 * 8;
  const unsigned short* srcB1 = Bsrc + (size_t)(n0 + ra1) * KD + kbeg + qa1 * 8;
  const int aO0 = (w * 16) * 32;
  const int aO1 = (64 + w * 16) * 32;

  const int wr = (w >> 1) * 64, wc = (w & 1) * 64;
  const int lr = lane & 15, q = lane >> 4;
  int offA[4], offB[4];
#pragma unroll
  for (int m = 0; m < 4; ++m) { int R = wr + m * 16 + lr; offA[m] = R * 32 + (q ^ ((R >> 1) & 3)) * 8; }
#pragma unroll
  for (int n = 0; n < 4; ++n) { int R = wc + n * 16 + lr; offB[n] = R * 32 + (q ^ ((R >> 1) & 3)) * 8; }

  f32x4 acc[4][4];
#pragma unroll
  for (int m = 0; m < 4; ++m)
#pragma unroll
    for (int n = 0; n < 4; ++n) acc[m][n] = (f32x4)0.f;

  // buffers: A_i = sm + i*4096, B_i = sm + 12288 + i*4096
  unsigned short* a0 = sm;          unsigned short* b0 = sm + 12288;
  unsigned short* a1 = sm + 4096;   unsigned short* b1 = sm + 16384;
  unsigned short* a2 = sm + 8192;   unsigned short* b2 = sm + 20480;

#define STG(T, BA, BB)                       \
  {                                          \
    const int ko = (T) * 32;                 \
    glds16(srcA0 + ko, (BA) + aO0);          \
    glds16(srcA1 + ko, (BA) + aO1);          \
    glds16(srcB0 + ko, (BB) + aO0);          \
    glds16(srcB1 + ko, (BB) + aO1);          \
  }

  // prologue: stage tiles 0 and 1; wait tile 0 only (tile 1 stays in flight)
  STG(0, a0, b0);
  STG(1, a1, b1);
  asm volatile("s_waitcnt vmcnt(4)" ::: "memory");
  __builtin_amdgcn_s_barrier();

  unsigned short *ca = a0, *cb = b0;   // compute buffer (tile t)
  unsigned short *na = a1, *nb = b1;   // next (tile t+1, loads may be in flight)
  unsigned short *wa = a2, *wb = b2;   // write target (tile t+2)

  for (int t = 0; t < NT; ++t) {
    if (t + 2 < NT) STG(t + 2, wa, wb);  // issue-early; stays in flight across barrier
    bf16x8 av[4], bv[4];
#pragma unroll
    for (int m = 0; m < 4; ++m) av[m] = *reinterpret_cast<const bf16x8*>(ca + offA[m]);
#pragma unroll
    for (int n = 0; n < 4; ++n) bv[n] = *reinterpret_cast<const bf16x8*>(cb + offB[n]);
#pragma unroll
    for (int m = 0; m < 4; ++m)
#pragma unroll
      for (int n = 0; n < 4; ++n)
        acc[m][n] = __builtin_amdgcn_mfma_f32_16x16x32_bf16(av[m], bv[n], acc[m][n], 0, 0, 0);
    if (t + 2 < NT) {
      asm volatile("s_waitcnt vmcnt(4)" ::: "memory");  // tile t+1 resident; t+2 in flight
    } else {
      asm volatile("s_waitcnt vmcnt(0)" ::: "memory");  // epilogue drain
    }
    __builtin_amdgcn_s_barrier();  // publish t+1; all reads of ca complete
    unsigned short* sp;
    sp = ca; ca = na; na = wa; wa = sp;
    sp = cb; cb = nb; nb = wb; wb = sp;
  }
#undef STG

  const int rbase = wr + (q << 2);
#pragma unroll
  for (int n = 0; n < 4; ++n) {
    const int col = n0 + wc + n * 16 + lr;
    const float bval = (MODE == 0 || kc == 0) ? bias[col] : 0.f;
#pragma unroll
    for (int m = 0; m < 4; ++m) {
#pragma unroll
      for (int r = 0; r < 4; ++r) {
        const int i = rbase + m * 16 + r;
        if (i < valid) {
          float v = acc[m][n][r] + bval;
          if (MODE == 0) {
            float sv = v / (1.f + __expf(-v));
            Hout[(size_t)(hbase + row0 + i) * IDIM + col] = f2bf(sv);
          } else {
            if (e < 8)
              atomicAdd(&out[(size_t)sTok[i] * CDIM + col], sGate[i] * v);
            else
              atomicAdd(&out[(size_t)(row0 + i) * CDIM + col], v);
          }
        }
      }
    }
  }
}

__global__ __launch_bounds__(256) void gemm1_kernel(
    const unsigned short* __restrict__ xb, const unsigned short* __restrict__ W1T,
    const float* __restrict__ be1, const float* __restrict__ bs1,
    const int* __restrict__ cnt, const int* __restrict__ offs,
    const int* __restrict__ list, unsigned short* __restrict__ H,
    const int* __restrict__ tbl) {
  __shared__ __align__(16) unsigned short sm[24576];
  const int y = blockIdx.y;
  if (y >= tbl[0]) return;
  gemm_block<0>(xb, W1T, be1, bs1, cnt, offs, list, nullptr, H, nullptr,
                tbl[1 + y], tbl[41 + y], 0, blockIdx.x, sm, nullptr, nullptr);
}

__global__ __launch_bounds__(256) void gemm2_kernel(
    const unsigned short* __restrict__ H, const unsigned short* __restrict__ W2T,
    const float* __restrict__ be2, const float* __restrict__ bs2,
    const int* __restrict__ cnt, const int* __restrict__ offs,
    const int* __restrict__ list, const float* __restrict__ gw,
    float* __restrict__ out, const int* __restrict__ tbl) {
  __shared__ __align__(16) unsigned short sm[24576];
  __shared__ int sTok[128];
  __shared__ float sGate[128];
  const int y = blockIdx.y;
  if (y >= tbl[0]) return;
  const int nt = blockIdx.x & 7, kc = blockIdx.x >> 3;
  gemm_block<1>(H, W2T, be2, bs2, cnt, offs, list, gw, nullptr, out,
                tbl[1 + y], tbl[41 + y], kc, nt, sm, sTok, sGate);
}

// ---------------- fallback GEMM (f32 weights direct; small-ws path) ----------
template <int MODE>
__global__ __launch_bounds__(256) void moe_gemm(
    const unsigned short* __restrict__ Abase, const float* __restrict__ Wr,
    const float* __restrict__ Wsh, const float* __restrict__ br,
    const float* __restrict__ bsh, const int* __restrict__ cnt,
    const int* __restrict__ offs, const int* __restrict__ list,
    const float* __restrict__ gw, unsigned short* __restrict__ Hout,
    float* __restrict__ out) {
  constexpr int KD = (MODE == 0) ? CDIM : IDIM;
  constexpr int ND = (MODE == 0) ? IDIM : CDIM;
  constexpr int KCH = (MODE == 0) ? KD : (KD / 4);
  const int nt = blockIdx.x, mt = blockIdx.y;
  const int e = (MODE == 0) ? blockIdx.z : (blockIdx.z % 9);
  const int kc = (MODE == 0) ? 0 : (blockIdx.z / 9);
  const int me = (e < 8) ? cnt[e] : NTOK;
  const int row0 = mt * 128;
  if (row0 >= me) return;
  const int valid = min(128, me - row0);
  const int n0 = nt * 128;
  const float* Bsrc = (e < 8) ? (Wr + (size_t)e * WSTRIDE) : Wsh;
  const float* bias = (e < 8) ? (br + (size_t)e * ND) : bsh;
  const int hbase = (e < 8) ? offs[e] : 2048;
  const int tid = threadIdx.x;

  __shared__ __align__(16) unsigned short sA[128][SBPAD];
  __shared__ __align__(16) unsigned short sB[128][SBPAD];
  __shared__ int rowSrc[128];
  __shared__ int sTok[128];
  __shared__ float sGate[128];

  if (tid < 128) {
    int i = tid, ic = min(i, valid - 1);
    if (MODE == 0) {
      rowSrc[i] = (e < 8) ? list[e * NTOK + row0 + ic] : (row0 + ic);
    } else {
      rowSrc[i] = hbase + row0 + i;
      if (e < 8) {
        sTok[i] = list[e * NTOK + row0 + ic];
        sGate[i] = (i < valid) ? gw[e * NTOK + row0 + i] : 0.f;
      }
    }
  }

  f32x4 acc[4][4];
#pragma unroll
  for (int m = 0; m < 4; ++m)
#pragma unroll
    for (int n = 0; n < 4; ++n) acc[m][n] = (f32x4)0.f;

  const int lane = tid & 63;
  const int wv = tid >> 6;
  const int wr = (wv >> 1) * 64, wc = (wv & 1) * 64;
  const int lr = lane & 15, lk = (lane >> 4) * 8;
  const int rowA = tid >> 2, kgA = (tid & 3) * 8;
  const int ncB = (tid & 63) * 2, kpB = tid >> 6;
  __syncthreads();

  const int kbeg = kc * KCH, kend = kbeg + KCH;
  uint4 pa0, pa1;
  float2 pb[8];

#define LOADTILE(K0)                                                            \
  {                                                                             \
    pa0 = *reinterpret_cast<const uint4*>(Abase + (size_t)rowSrc[rowA] * KD + (K0) + kgA);      \
    pa1 = *reinterpret_cast<const uint4*>(Abase + (size_t)rowSrc[rowA + 64] * KD + (K0) + kgA); \
    const float* Bp = Bsrc + (size_t)((K0) + kpB * 8) * ND + n0 + ncB;          \
    _Pragma("unroll") for (int j = 0; j < 8; ++j)                               \
        pb[j] = *reinterpret_cast<const float2*>(Bp + (size_t)j * ND);          \
  }

  LOADTILE(kbeg);
  for (int k0 = kbeg; k0 < kend; k0 += 32) {
    __syncthreads();
    *reinterpret_cast<uint4*>(&sA[rowA][kgA]) = pa0;
    *reinterpret_cast<uint4*>(&sA[rowA + 64][kgA]) = pa1;
    {
      bf16x8 q0, q1;
#pragma unroll
      for (int j = 0; j < 8; ++j) { q0[j] = (__bf16)pb[j].x; q1[j] = (__bf16)pb[j].y; }
      *reinterpret_cast<bf16x8*>(&sB[ncB][kpB * 8]) = q0;
      *reinterpret_cast<bf16x8*>(&sB[ncB + 1][kpB * 8]) = q1;
    }
    __syncthreads();
    if (k0 + 32 < kend) LOADTILE(k0 + 32);
    bf16x8 av[4], bv[4];
#pragma unroll
    for (int m = 0; m < 4; ++m)
      av[m] = *reinterpret_cast<const bf16x8*>(&sA[wr + m * 16 + lr][lk]);
#pragma unroll
    for (int n = 0; n < 4; ++n)
      bv[n] = *reinterpret_cast<const bf16x8*>(&sB[wc + n * 16 + lr][lk]);
#pragma unroll
    for (int m = 0; m < 4; ++m)
#pragma unroll
      for (int n = 0; n < 4; ++n)
        acc[m][n] = __builtin_amdgcn_mfma_f32_16x16x32_bf16(av[m], bv[n], acc[m][n], 0, 0, 0);
  }
#undef LOADTILE

  const int rbase = wr + ((lane >> 4) << 2);
#pragma unroll
  for (int n = 0; n < 4; ++n) {
    const int col = n0 + wc + n * 16 + lr;
    const float bval = (MODE == 0 || kc == 0) ? bias[col] : 0.f;
#pragma unroll
    for (int m = 0; m < 4; ++m) {
#pragma unroll
      for (int r = 0; r < 4; ++r) {
        const int i = rbase + m * 16 + r;
        if (i < valid) {
          float v = acc[m][n][r] + bval;
          if (MODE == 0) {
            float sv = v / (1.f + __expf(-v));
            Hout[(size_t)(hbase + row0 + i) * IDIM + col] = f2bf(sv);
          } else {
            if (e < 8)
              atomicAdd(&out[(size_t)sTok[i] * CDIM + col], sGate[i] * v);
            else
              atomicAdd(&out[(size_t)(row0 + i) * CDIM + col], v);
          }
        }
      }
    }
  }
}

extern "C" void kernel_launch(void* const* d_in, const int* in_sizes, int n_in,
                              void* d_out, int out_size, void* d_ws, size_t ws_size,
                              hipStream_t stream) {
  const float* x = (const float*)d_in[0];
  const float* Wr1 = (const float*)d_in[1];
  const float* br1 = (const float*)d_in[2];
  const float* Wr2 = (const float*)d_in[3];
  const float* br2 = (const float*)d_in[4];
  const float* Ws1 = (const float*)d_in[5];
  const float* bs1 = (const float*)d_in[6];
  const float* Ws2 = (const float*)d_in[7];
  const float* bs2 = (const float*)d_in[8];
  const float* We1 = (const float*)d_in[9];
  const float* be1 = (const float*)d_in[10];
  const float* We2 = (const float*)d_in[11];
  const float* be2 = (const float*)d_in[12];
  float* out = (float*)d_out;

  char* ws = (char*)d_ws;
  unsigned short* xb = (unsigned short*)(ws + 0);            // 2 MB
  int* ti = (int*)(ws + 2097152);
  float* tw = (float*)(ws + 2105344);
  int* cnt = (int*)(ws + 2113536);
  int* offs = (int*)(ws + 2113792);
  int* list = (int*)(ws + 2114048);
  float* gw = (float*)(ws + 2146816);
  unsigned short* H = (unsigned short*)(ws + 2179584);       // 24 MB, ends 27345408
  int* tbl = (int*)(ws + 27345408);                          // 512 B
  const bool huge = ws_size >= 179ull * 1024 * 1024;
  unsigned short* W1T = (unsigned short*)(ws + 27345920ull);   // 72 MB
  unsigned short* W2T = (unsigned short*)(ws + 102843904ull);  // 72 MB

  init_cast_kernel<<<1024, 256, 0, stream>>>(x, xb, out);
  router_kernel<<<NTOK / RT, 256, 0, stream>>>(x, Wr1, br1, Wr2, br2, ti, tw);
  build_lists_kernel<<<8, 1024, 0, stream>>>(ti, tw, cnt, list, gw);
  offsets_kernel<<<1, 64, 0, stream>>>(cnt, offs, tbl);

  if (huge) {
    transpose_cvt<CDIM, IDIM><<<dim3(32, 8, 9), 256, 0, stream>>>(We1, Ws1, W1T);
    transpose_cvt<IDIM, CDIM><<<dim3(8, 32, 9), 256, 0, stream>>>(We2, Ws2, W2T);
    gemm1_kernel<<<dim3(32, 32), 256, 0, stream>>>(xb, W1T, be1, bs1, cnt, offs,
                                                   list, H, tbl);
    gemm2_kernel<<<dim3(32, 32), 256, 0, stream>>>(H, W2T, be2, bs2, cnt, offs,
                                                   list, gw, out, tbl);
  } else {
    moe_gemm<0><<<dim3(32, 8, 9), 256, 0, stream>>>(xb, We1, Ws1, be1, bs1, cnt, offs, list, gw, H, out);
    moe_gemm<1><<<dim3(8, 8, 36), 256, 0, stream>>>(H, We2, Ws2, be2, bs2, cnt, offs, list, gw, nullptr, out);
  }
}

// Round 7
// 312.589 us; speedup vs baseline: 1.6311x; 1.1515x over previous
//
#include <hip/hip_runtime.h>

#define NTOK 1024
#define CDIM 1024
#define CRDIM 256
#define ENUM 8
#define IDIM 4096
#define WSTRIDE 4194304ull  // C*I elements per expert weight matrix
#define SBPAD 56            // fallback LDS row stride in ushorts

typedef __bf16 bf16x8 __attribute__((ext_vector_type(8)));
typedef float f32x4 __attribute__((ext_vector_type(4)));

typedef const unsigned int __attribute__((address_space(1))) gu32;
typedef unsigned int __attribute__((address_space(3))) lu32;

__device__ __forceinline__ void glds16(const unsigned short* g, unsigned short* l) {
  __builtin_amdgcn_global_load_lds((gu32*)g, (lu32*)l, 16, 0, 0);
}

__device__ __forceinline__ unsigned short f2bf(float f) {
  union { float f; unsigned int u; } v; v.f = f;
  unsigned int r = v.u + 0x7FFFu + ((v.u >> 16) & 1u);  // RNE
  return (unsigned short)(r >> 16);
}

// ================= device building blocks =================

__device__ __forceinline__ void init_block(int b, const float* __restrict__ x,
                                           unsigned short* __restrict__ xb) {
  int t = b * 256 + threadIdx.x;
  float4 v = reinterpret_cast<const float4*>(x)[t];
  ushort4 o;
  o.x = f2bf(v.x); o.y = f2bf(v.y); o.z = f2bf(v.z); o.w = f2bf(v.w);
  reinterpret_cast<ushort4*>(xb)[t] = o;
}

// ---- transpose + f32->bf16: src [KD][ND] tile -> dst [ND][KD] ----
template <int KD, int ND>
__device__ __forceinline__ void transpose_block(
    const float* __restrict__ src, unsigned short* __restrict__ dse,
    int n0, int k0, unsigned short* lt /* 128*136 ushorts */) {
  const int tid = threadIdx.x;
  const int bn = tid >> 3, bk0 = tid & 7;
#pragma unroll
  for (int i = 0; i < 4; ++i) {
    const int bk = bk0 + 8 * i;
    const float* sp = src + (size_t)(k0 + 4 * bk) * ND + n0 + 4 * bn;
    float4 r0 = *reinterpret_cast<const float4*>(sp);
    float4 r1 = *reinterpret_cast<const float4*>(sp + ND);
    float4 r2 = *reinterpret_cast<const float4*>(sp + 2 * (size_t)ND);
    float4 r3 = *reinterpret_cast<const float4*>(sp + 3 * (size_t)ND);
    ushort4 c;
    c.x = f2bf(r0.x); c.y = f2bf(r1.x); c.z = f2bf(r2.x); c.w = f2bf(r3.x);
    *reinterpret_cast<ushort4*>(&lt[(4 * bn + 0) * 136 + 4 * bk]) = c;
    c.x = f2bf(r0.y); c.y = f2bf(r1.y); c.z = f2bf(r2.y); c.w = f2bf(r3.y);
    *reinterpret_cast<ushort4*>(&lt[(4 * bn + 1) * 136 + 4 * bk]) = c;
    c.x = f2bf(r0.z); c.y = f2bf(r1.z); c.z = f2bf(r2.z); c.w = f2bf(r3.z);
    *reinterpret_cast<ushort4*>(&lt[(4 * bn + 2) * 136 + 4 * bk]) = c;
    c.x = f2bf(r0.w); c.y = f2bf(r1.w); c.z = f2bf(r2.w); c.w = f2bf(r3.w);
    *reinterpret_cast<ushort4*>(&lt[(4 * bn + 3) * 136 + 4 * bk]) = c;
  }
  __syncthreads();
#pragma unroll
  for (int p = 0; p < 2; ++p) {
    const int n = (tid >> 2) + 64 * p;
    const int seg = (tid & 3) * 32;
    const uint4 d0 = *reinterpret_cast<const uint4*>(&lt[n * 136 + seg]);
    const uint4 d1 = *reinterpret_cast<const uint4*>(&lt[n * 136 + seg + 8]);
    const uint4 d2 = *reinterpret_cast<const uint4*>(&lt[n * 136 + seg + 16]);
    const uint4 d3 = *reinterpret_cast<const uint4*>(&lt[n * 136 + seg + 24]);
    unsigned short* o = dse + (size_t)(n0 + n) * KD + k0 + seg;
    reinterpret_cast<uint4*>(o)[0] = d0;
    reinterpret_cast<uint4*>(o)[1] = d1;
    reinterpret_cast<uint4*>(o)[2] = d2;
    reinterpret_cast<uint4*>(o)[3] = d3;
  }
}

// ---- 3-buffer pipelined MFMA GEMM block ----
// MODE 0: H[hrow] = silu(Xg @ W1T^T + b1)        (bf16 store)
// MODE 1: pout[kc][hrow] = H @ W2T^T (+b2@kc0)   (f32 plain store, split-K=4)
template <int MODE>
__device__ __forceinline__ void gemm_block(
    const unsigned short* __restrict__ Abase, const unsigned short* __restrict__ Bt,
    const float* __restrict__ br, const float* __restrict__ bsh,
    const int* __restrict__ cnt, const int* __restrict__ offs,
    const int* __restrict__ list, unsigned short* __restrict__ Hout,
    float* __restrict__ pout, int e, int row0, int kc, int nt,
    unsigned short* sm /* 24576 ushorts */) {
  constexpr int KD = (MODE == 0) ? CDIM : IDIM;
  constexpr int ND = (MODE == 0) ? IDIM : CDIM;
  constexpr int KCH = (MODE == 0) ? KD : (KD / 4);
  constexpr int NT = KCH / 32;
  const int me = (e < 8) ? cnt[e] : NTOK;
  const int valid = min(128, me - row0);
  const int n0 = nt * 128;
  const unsigned short* Bsrc = Bt + (size_t)e * WSTRIDE;
  const float* bias = (e < 8) ? (br + (size_t)e * ND) : bsh;
  const int hbase = (e < 8) ? offs[e] : 2048;
  const int tid = threadIdx.x;
  const int lane = tid & 63, w = tid >> 6;

  // staging: wave w covers rows [16w,16w+16) and [64+16w,..); swizzled k-chunks
  const int rl = lane >> 2, cs = lane & 3;
  const int ra0 = w * 16 + rl, ra1 = 64 + w * 16 + rl;
  const int qa0 = cs ^ ((ra0 >> 1) & 3), qa1 = cs ^ ((ra1 >> 1) & 3);
  const int kbeg = kc * KCH;
  size_t arow0, arow1;
  if (MODE == 0) {
    if (e < 8) {
      arow0 = (size_t)list[e * NTOK + row0 + min(ra0, valid - 1)];
      arow1 = (size_t)list[e * NTOK + row0 + min(ra1, valid - 1)];
    } else { arow0 = (size_t)(row0 + ra0); arow1 = (size_t)(row0 + ra1); }
  } else { arow0 = (size_t)(hbase + row0 + ra0); arow1 = (size_t)(hbase + row0 + ra1); }
  const unsigned short* srcA0 = Abase + arow0 * KD + kbeg + qa0 * 8;
  const unsigned short* srcA1 = Abase + arow1 * KD + kbeg + qa1 * 8;
  const unsigned short* srcB0 = Bsrc + (size_t)(n0 + ra0) * KD + kbeg + qa0 * 8;
  const unsigned short* srcB1 = Bsrc + (size_t)(n0 + ra1) * KD + kbeg + qa1 * 8;
  const int aO0 = (w * 16) * 32;
  const int aO1 = (64 + w * 16) * 32;

  const int wr = (w >> 1) * 64, wc = (w & 1) * 64;
  const int lr = lane & 15, q = lane >> 4;
  int offA[4], offB[4];
#pragma unroll
  for (int m = 0; m < 4; ++m) { int R = wr + m * 16 + lr; offA[m] = R * 32 + (q ^ ((R >> 1) & 3)) * 8; }
#pragma unroll
  for (int n = 0; n < 4; ++n) { int R = wc + n * 16 + lr; offB[n] = R * 32 + (q ^ ((R >> 1) & 3)) * 8; }

  f32x4 acc[4][4];
#pragma unroll
  for (int m = 0; m < 4; ++m)
#pragma unroll
    for (int n = 0; n < 4; ++n) acc[m][n] = (f32x4)0.f;

  // buffers: A_i = sm + i*4096, B_i = sm + 12288 + i*4096
  unsigned short* a0 = sm;          unsigned short* b0 = sm + 12288;
  unsigned short* a1 = sm + 4096;   unsigned short* b1 = sm + 16384;
  unsigned short* a2 = sm + 8192;   unsigned short* b2 = sm + 20480;

#define STG(T, BA, BB)                       \
  {                                          \
    const int ko = (T) * 32;                 \
    glds16(srcA0 + ko, (BA) + aO0);          \
    glds16(srcA1 + ko, (BA) + aO1);          \
    glds16(srcB0 + ko, (BB) + aO0);          \
    glds16(srcB1 + ko, (BB) + aO1);          \
  }

  STG(0, a0, b0);
  STG(1, a1, b1);
  asm volatile("s_waitcnt vmcnt(4)" ::: "memory");
  __builtin_amdgcn_s_barrier();

  unsigned short *ca = a0, *cb = b0;
  unsigned short *na = a1, *nb = b1;
  unsigned short *wa = a2, *wb = b2;

  for (int t = 0; t < NT; ++t) {
    if (t + 2 < NT) STG(t + 2, wa, wb);
    bf16x8 av[4], bv[4];
#pragma unroll
    for (int m = 0; m < 4; ++m) av[m] = *reinterpret_cast<const bf16x8*>(ca + offA[m]);
#pragma unroll
    for (int n = 0; n < 4; ++n) bv[n] = *reinterpret_cast<const bf16x8*>(cb + offB[n]);
#pragma unroll
    for (int m = 0; m < 4; ++m)
#pragma unroll
      for (int n = 0; n < 4; ++n)
        acc[m][n] = __builtin_amdgcn_mfma_f32_16x16x32_bf16(av[m], bv[n], acc[m][n], 0, 0, 0);
    if (t + 2 < NT) {
      asm volatile("s_waitcnt vmcnt(4)" ::: "memory");
    } else {
      asm volatile("s_waitcnt vmcnt(0)" ::: "memory");
    }
    __builtin_amdgcn_s_barrier();
    unsigned short* sp;
    sp = ca; ca = na; na = wa; wa = sp;
    sp = cb; cb = nb; nb = wb; wb = sp;
  }
#undef STG

  const int rbase = wr + (q << 2);
#pragma unroll
  for (int n = 0; n < 4; ++n) {
    const int col = n0 + wc + n * 16 + lr;
    const float bval = (MODE == 0 || kc == 0) ? bias[col] : 0.f;
#pragma unroll
    for (int m = 0; m < 4; ++m) {
#pragma unroll
      for (int r = 0; r < 4; ++r) {
        const int i = rbase + m * 16 + r;
        if (i < valid) {
          float v = acc[m][n][r] + bval;
          if (MODE == 0) {
            float sv = v / (1.f + __expf(-v));
            Hout[(size_t)(hbase + row0 + i) * IDIM + col] = f2bf(sv);
          } else {
            pout[((size_t)kc * 3072 + hbase + row0 + i) * CDIM + col] = v;
          }
        }
      }
    }
  }
}

// ================= kernels =================

// ---------------- router: gates + top-2 ----------------
#define RT 8
__global__ __launch_bounds__(256) void router_kernel(
    const float* __restrict__ x, const float* __restrict__ Wr1,
    const float* __restrict__ br1, const float* __restrict__ Wr2,
    const float* __restrict__ br2, int* __restrict__ ti,
    float* __restrict__ tw) {
  __shared__ float xs[RT][CDIM];
  __shared__ float hs[RT][CRDIM];
  __shared__ float lg[RT][ENUM];
  const int tid = threadIdx.x;
  const int tok0 = blockIdx.x * RT;
  for (int r = 0; r < RT; ++r) {
    float4 v = reinterpret_cast<const float4*>(x + (size_t)(tok0 + r) * CDIM)[tid];
    *reinterpret_cast<float4*>(&xs[r][tid * 4]) = v;
  }
  __syncthreads();
  float acc[RT];
#pragma unroll
  for (int r = 0; r < RT; ++r) acc[r] = 0.f;
  const int j = tid;
  for (int i = 0; i < CDIM; ++i) {
    float w = Wr1[(size_t)i * CRDIM + j];
#pragma unroll
    for (int r = 0; r < RT; ++r) acc[r] += xs[r][i] * w;
  }
  float b = br1[j];
#pragma unroll
  for (int r = 0; r < RT; ++r) hs[r][j] = fmaxf(acc[r] + b, 0.f);
  __syncthreads();
  if (tid < RT * ENUM) {
    int r = tid >> 3, e = tid & 7;
    float a = 0.f;
    for (int i = 0; i < CRDIM; ++i) a += hs[r][i] * Wr2[(size_t)i * ENUM + e];
    lg[r][e] = a + br2[e];
  }
  __syncthreads();
  if (tid < RT) {
    int r = tid;
    float m = lg[r][0];
#pragma unroll
    for (int e = 1; e < 8; ++e) m = fmaxf(m, lg[r][e]);
    float s = 0.f, g[8];
#pragma unroll
    for (int e = 0; e < 8; ++e) { g[e] = expf(lg[r][e] - m); s += g[e]; }
    float inv = 1.f / s;
    int i0 = 0; float g0 = -1.f;
#pragma unroll
    for (int e = 0; e < 8; ++e) { float ge = g[e] * inv; if (ge > g0) { g0 = ge; i0 = e; } }
    int i1 = 0; float g1 = -2.f;
#pragma unroll
    for (int e = 0; e < 8; ++e) { float ge = g[e] * inv; if (e != i0 && ge > g1) { g1 = ge; i1 = e; } }
    float w0 = 1.f / (1.f + expf((g1 - g0) * 0.5f));
    int n = tok0 + r;
    ti[2 * n] = i0; ti[2 * n + 1] = i1;
    tw[2 * n] = w0; tw[2 * n + 1] = 1.f - w0;
  }
}

// prep1: [0,2304) W1 transpose; [2304,3328) x->bf16 cast
__global__ __launch_bounds__(256) void prep1_kernel(
    const float* __restrict__ x, unsigned short* __restrict__ xb,
    const float* __restrict__ We1, const float* __restrict__ Ws1,
    unsigned short* __restrict__ W1T) {
  __shared__ __align__(16) unsigned short lt[128 * 136];
  const int b = blockIdx.x;
  if (b < 2304) {
    const int e = b >> 8, rem = b & 255;
    const float* src = (e < 8) ? (We1 + (size_t)e * WSTRIDE) : Ws1;
    transpose_block<CDIM, IDIM>(src, W1T + (size_t)e * WSTRIDE,
                                (rem & 31) * 128, (rem >> 5) * 128, lt);
  } else {
    init_block(b - 2304, x, xb);
  }
}

__global__ __launch_bounds__(1024) void build_lists_kernel(
    const int* __restrict__ ti, const float* __restrict__ tw,
    int* __restrict__ cnt, int* __restrict__ list, float* __restrict__ gw,
    int* __restrict__ tokslot) {
  __shared__ int s[NTOK];
  const int e = blockIdx.x, n = threadIdx.x;
  int a = ti[2 * n], b = ti[2 * n + 1];
  float w = (a == e) ? tw[2 * n] : ((b == e) ? tw[2 * n + 1] : 0.f);
  int flag = (a == e || b == e) ? 1 : 0;
  s[n] = flag;
  __syncthreads();
  for (int off = 1; off < NTOK; off <<= 1) {
    int v = (n >= off) ? s[n - off] : 0;
    __syncthreads();
    s[n] += v;
    __syncthreads();
  }
  if (flag) {
    int pos = s[n] - 1;
    list[e * NTOK + pos] = n; gw[e * NTOK + pos] = w;
    int slot = (a == e) ? 0 : 1;
    tokslot[2 * n + slot] = (e << 16) | pos;
  }
  if (n == NTOK - 1) cnt[e] = s[n];
}

// offsets + M-tile table: tbl[0]=ntt; tbl[1+i]=expert; tbl[41+i]=row0
__global__ void offsets_kernel(const int* __restrict__ cnt, int* __restrict__ offs,
                               int* __restrict__ tbl) {
  if (threadIdx.x == 0) {
    int o = 0;
    for (int e = 0; e < 8; ++e) { offs[e] = o; o += cnt[e]; }
    offs[8] = o;
    int k = 0;
    for (int e = 0; e < 9; ++e) {
      int me = (e < 8) ? cnt[e] : NTOK;
      for (int r0 = 0; r0 < me; r0 += 128) { tbl[1 + k] = e; tbl[41 + k] = r0; ++k; }
    }
    tbl[0] = k;
  }
}

// fused: per 13 blocks, 4 gemm1 tiles + 9 W2-transpose tiles (interleaved residency)
__global__ __launch_bounds__(256) void g1t2_kernel(
    const unsigned short* __restrict__ xb, const unsigned short* __restrict__ W1T,
    const float* __restrict__ be1, const float* __restrict__ bs1,
    const int* __restrict__ cnt, const int* __restrict__ offs,
    const int* __restrict__ list, unsigned short* __restrict__ H,
    const int* __restrict__ tbl, const float* __restrict__ We2,
    const float* __restrict__ Ws2, unsigned short* __restrict__ W2T) {
  __shared__ __align__(16) unsigned short sm[24576];
  const int b = blockIdx.x;
  const int g = b % 13, qq = b / 13;
  if (g < 4) {
    const int s = qq * 4 + g;       // [0,1024)
    const int nt = s & 31, y = s >> 5;
    if (y >= tbl[0]) return;
    gemm_block<0>(xb, W1T, be1, bs1, cnt, offs, list, H, nullptr,
                  tbl[1 + y], tbl[41 + y], 0, nt, sm);
  } else {
    const int t = qq * 9 + (g - 4);  // [0,2304)
    const int e = t >> 8, rem = t & 255;
    const float* src = (e < 8) ? (We2 + (size_t)e * WSTRIDE) : Ws2;
    transpose_block<IDIM, CDIM>(src, W2T + (size_t)e * WSTRIDE,
                                (rem & 7) * 128, (rem >> 3) * 128, sm);
  }
}

__global__ __launch_bounds__(256) void gemm2_kernel(
    const unsigned short* __restrict__ H, const unsigned short* __restrict__ W2T,
    const float* __restrict__ be2, const float* __restrict__ bs2,
    const int* __restrict__ cnt, const int* __restrict__ offs,
    float* __restrict__ pout, const int* __restrict__ tbl) {
  __shared__ __align__(16) unsigned short sm[24576];
  const int y = blockIdx.y;
  if (y >= tbl[0]) return;
  const int nt = blockIdx.x & 7, kc = blockIdx.x >> 3;
  gemm_block<1>(H, W2T, be2, bs2, cnt, offs, nullptr, nullptr, pout,
                tbl[1 + y], tbl[41 + y], kc, nt, sm);
}

// out[tok][c] = sum_kc( pout[kc][shared] + g0*pout[kc][h0] + g1*pout[kc][h1] )
__global__ __launch_bounds__(256) void reduce_kernel(
    const float* __restrict__ pout, const int* __restrict__ tokslot,
    const float* __restrict__ tw, const int* __restrict__ offs,
    float* __restrict__ out) {
  const int tok = blockIdx.x;
  const int c = threadIdx.x * 4;
  const int t0 = tokslot[2 * tok], t1 = tokslot[2 * tok + 1];
  const float g0 = tw[2 * tok], g1 = tw[2 * tok + 1];
  const int r0 = offs[t0 >> 16] + (t0 & 0xffff);
  const int r1 = offs[t1 >> 16] + (t1 & 0xffff);
  const int rs = 2048 + tok;
  float4 acc; acc.x = 0.f; acc.y = 0.f; acc.z = 0.f; acc.w = 0.f;
#pragma unroll
  for (int kc = 0; kc < 4; ++kc) {
    const float* base = pout + (size_t)kc * 3072 * CDIM;
    float4 a = *reinterpret_cast<const float4*>(base + (size_t)rs * CDIM + c);
    float4 b = *reinterpret_cast<const float4*>(base + (size_t)r0 * CDIM + c);
    float4 d = *reinterpret_cast<const float4*>(base + (size_t)r1 * CDIM + c);
    acc.x += a.x + g0 * b.x + g1 * d.x;
    acc.y += a.y + g0 * b.y + g1 * d.y;
    acc.z += a.z + g0 * b.z + g1 * d.z;
    acc.w += a.w + g0 * b.w + g1 * d.w;
  }
  *reinterpret_cast<float4*>(out + (size_t)tok * CDIM + c) = acc;
}

// ---------------- fallback GEMM (f32 weights direct; small-ws path) ----------
template <int MODE>
__global__ __launch_bounds__(256) void moe_gemm(
    const unsigned short* __restrict__ Abase, const float* __restrict__ Wr,
    const float* __restrict__ Wsh, const float* __restrict__ br,
    const float* __restrict__ bsh, const int* __restrict__ cnt,
    const int* __restrict__ offs, const int* __restrict__ list,
    const float* __restrict__ gw, unsigned short* __restrict__ Hout,
    float* __restrict__ out) {
  constexpr int KD = (MODE == 0) ? CDIM : IDIM;
  constexpr int ND = (MODE == 0) ? IDIM : CDIM;
  constexpr int KCH = (MODE == 0) ? KD : (KD / 4);
  const int nt = blockIdx.x, mt = blockIdx.y;
  const int e = (MODE == 0) ? blockIdx.z : (blockIdx.z % 9);
  const int kc = (MODE == 0) ? 0 : (blockIdx.z / 9);
  const int me = (e < 8) ? cnt[e] : NTOK;
  const int row0 = mt * 128;
  if (row0 >= me) return;
  const int valid = min(128, me - row0);
  const int n0 = nt * 128;
  const float* Bsrc = (e < 8) ? (Wr + (size_t)e * WSTRIDE) : Wsh;
  const float* bias = (e < 8) ? (br + (size_t)e * ND) : bsh;
  const int hbase = (e < 8) ? offs[e] : 2048;
  const int tid = threadIdx.x;

  __shared__ __align__(16) unsigned short sA[128][SBPAD];
  __shared__ __align__(16) unsigned short sB[128][SBPAD];
  __shared__ int rowSrc[128];
  __shared__ int sTok[128];
  __shared__ float sGate[128];

  if (tid < 128) {
    int i = tid, ic = min(i, valid - 1);
    if (MODE == 0) {
      rowSrc[i] = (e < 8) ? list[e * NTOK + row0 + ic] : (row0 + ic);
    } else {
      rowSrc[i] = hbase + row0 + i;
      if (e < 8) {
        sTok[i] = list[e * NTOK + row0 + ic];
        sGate[i] = (i < valid) ? gw[e * NTOK + row0 + i] : 0.f;
      }
    }
  }

  f32x4 acc[4][4];
#pragma unroll
  for (int m = 0; m < 4; ++m)
#pragma unroll
    for (int n = 0; n < 4; ++n) acc[m][n] = (f32x4)0.f;

  const int lane = tid & 63;
  const int wv = tid >> 6;
  const int wr = (wv >> 1) * 64, wc = (wv & 1) * 64;
  const int lr = lane & 15, lk = (lane >> 4) * 8;
  const int rowA = tid >> 2, kgA = (tid & 3) * 8;
  const int ncB = (tid & 63) * 2, kpB = tid >> 6;
  __syncthreads();

  const int kbeg = kc * KCH, kend = kbeg + KCH;
  uint4 pa0, pa1;
  float2 pb[8];

#define LOADTILE(K0)                                                            \
  {                                                                             \
    pa0 = *reinterpret_cast<const uint4*>(Abase + (size_t)rowSrc[rowA] * KD + (K0) + kgA);      \
    pa1 = *reinterpret_cast<const uint4*>(Abase + (size_t)rowSrc[rowA + 64] * KD + (K0) + kgA); \
    const float* Bp = Bsrc + (size_t)((K0) + kpB * 8) * ND + n0 + ncB;          \
    _Pragma("unroll") for (int j = 0; j < 8; ++j)                               \
        pb[j] = *reinterpret_cast<const float2*>(Bp + (size_t)j * ND);          \
  }

  LOADTILE(kbeg);
  for (int k0 = kbeg; k0 < kend; k0 += 32) {
    __syncthreads();
    *reinterpret_cast<uint4*>(&sA[rowA][kgA]) = pa0;
    *reinterpret_cast<uint4*>(&sA[rowA + 64][kgA]) = pa1;
    {
      bf16x8 q0, q1;
#pragma unroll
      for (int j = 0; j < 8; ++j) { q0[j] = (__bf16)pb[j].x; q1[j] = (__bf16)pb[j].y; }
      *reinterpret_cast<bf16x8*>(&sB[ncB][kpB * 8]) = q0;
      *reinterpret_cast<bf16x8*>(&sB[ncB + 1][kpB * 8]) = q1;
    }
    __syncthreads();
    if (k0 + 32 < kend) LOADTILE(k0 + 32);
    bf16x8 av[4], bv[4];
#pragma unroll
    for (int m = 0; m < 4; ++m)
      av[m] = *reinterpret_cast<const bf16x8*>(&sA[wr + m * 16 + lr][lk]);
#pragma unroll
    for (int n = 0; n < 4; ++n)
      bv[n] = *reinterpret_cast<const bf16x8*>(&sB[wc + n * 16 + lr][lk]);
#pragma unroll
    for (int m = 0; m < 4; ++m)
#pragma unroll
      for (int n = 0; n < 4; ++n)
        acc[m][n] = __builtin_amdgcn_mfma_f32_16x16x32_bf16(av[m], bv[n], acc[m][n], 0, 0, 0);
  }
#undef LOADTILE

  const int rbase = wr + ((lane >> 4) << 2);
#pragma unroll
  for (int n = 0; n < 4; ++n) {
    const int col = n0 + wc + n * 16 + lr;
    const float bval = (MODE == 0 || kc == 0) ? bias[col] : 0.f;
#pragma unroll
    for (int m = 0; m < 4; ++m) {
#pragma unroll
      for (int r = 0; r < 4; ++r) {
        const int i = rbase + m * 16 + r;
        if (i < valid) {
          float v = acc[m][n][r] + bval;
          if (MODE == 0) {
            float sv = v / (1.f + __expf(-v));
            Hout[(size_t)(hbase + row0 + i) * IDIM + col] = f2bf(sv);
          } else {
            if (e < 8)
              atomicAdd(&out[(size_t)sTok[i] * CDIM + col], sGate[i] * v);
            else
              atomicAdd(&out[(size_t)(row0 + i) * CDIM + col], v);
          }
        }
      }
    }
  }
}

__global__ __launch_bounds__(256) void init_cast_kernel(
    const float* __restrict__ x, unsigned short* __restrict__ xb) {
  init_block(blockIdx.x, x, xb);
}

extern "C" void kernel_launch(void* const* d_in, const int* in_sizes, int n_in,
                              void* d_out, int out_size, void* d_ws, size_t ws_size,
                              hipStream_t stream) {
  const float* x = (const float*)d_in[0];
  const float* Wr1 = (const float*)d_in[1];
  const float* br1 = (const float*)d_in[2];
  const float* Wr2 = (const float*)d_in[3];
  const float* br2 = (const float*)d_in[4];
  const float* Ws1 = (const float*)d_in[5];
  const float* bs1 = (const float*)d_in[6];
  const float* Ws2 = (const float*)d_in[7];
  const float* bs2 = (const float*)d_in[8];
  const float* We1 = (const float*)d_in[9];
  const float* be1 = (const float*)d_in[10];
  const float* We2 = (const float*)d_in[11];
  const float* be2 = (const float*)d_in[12];
  float* out = (float*)d_out;

  char* ws = (char*)d_ws;
  unsigned short* xb = (unsigned short*)(ws + 0);            // 2 MB
  int* ti = (int*)(ws + 2097152);
  float* tw = (float*)(ws + 2105344);
  int* cnt = (int*)(ws + 2113536);
  int* offs = (int*)(ws + 2113792);
  int* list = (int*)(ws + 2114048);
  float* gw = (float*)(ws + 2146816);
  unsigned short* H = (unsigned short*)(ws + 2179584);       // 24 MB -> 27345408
  int* tbl = (int*)(ws + 27345408);                          // 512 B
  int* tokslot = (int*)(ws + 27345920);                      // 8 KB -> 27354112
  unsigned short* W1T = (unsigned short*)(ws + 27354112ull);   // 72 MB -> 102851584
  float* pout = (float*)(ws + 27354112ull);                    // 48 MB, overlays W1T
  unsigned short* W2T = (unsigned short*)(ws + 102851584ull);  // 72 MB -> 178349056
  const bool huge = ws_size >= 179ull * 1024 * 1024;

  if (huge) {
    router_kernel<<<NTOK / RT, 256, 0, stream>>>(x, Wr1, br1, Wr2, br2, ti, tw);
    prep1_kernel<<<3328, 256, 0, stream>>>(x, xb, We1, Ws1, W1T);
    build_lists_kernel<<<8, 1024, 0, stream>>>(ti, tw, cnt, list, gw, tokslot);
    offsets_kernel<<<1, 64, 0, stream>>>(cnt, offs, tbl);
    g1t2_kernel<<<3328, 256, 0, stream>>>(xb, W1T, be1, bs1, cnt, offs, list, H,
                                          tbl, We2, Ws2, W2T);
    gemm2_kernel<<<dim3(32, 32), 256, 0, stream>>>(H, W2T, be2, bs2, cnt, offs,
                                                   pout, tbl);
    reduce_kernel<<<1024, 256, 0, stream>>>(pout, tokslot, tw, offs, out);
  } else {
    hipMemsetAsync(out, 0, (size_t)out_size * sizeof(float), stream);
    init_cast_kernel<<<1024, 256, 0, stream>>>(x, xb);
    router_kernel<<<NTOK / RT, 256, 0, stream>>>(x, Wr1, br1, Wr2, br2, ti, tw);
    build_lists_kernel<<<8, 1024, 0, stream>>>(ti, tw, cnt, list, gw, tokslot);
    offsets_kernel<<<1, 64, 0, stream>>>(cnt, offs, tbl);
    moe_gemm<0><<<dim3(32, 8, 9), 256, 0, stream>>>(xb, We1, Ws1, be1, bs1, cnt, offs, list, gw, H, out);
    moe_gemm<1><<<dim3(8, 8, 36), 256, 0, stream>>>(H, We2, Ws2, be2, bs2, cnt, offs, list, gw, nullptr, out);
  }
}

// Round 8
// 294.649 us; speedup vs baseline: 1.7304x; 1.0609x over previous
//
#include <hip/hip_runtime.h>

#define NTOK 1024
#define CDIM 1024
#define CRDIM 256
#define ENUM 8
#define IDIM 4096
#define WSTRIDE 4194304ull  // C*I elements per expert weight matrix

typedef __bf16 bf16x8 __attribute__((ext_vector_type(8)));
typedef float f32x4 __attribute__((ext_vector_type(4)));

typedef const unsigned int __attribute__((address_space(1))) gu32;
typedef unsigned int __attribute__((address_space(3))) lu32;

__device__ __forceinline__ void glds16(const unsigned short* g, unsigned short* l) {
  __builtin_amdgcn_global_load_lds((gu32*)g, (lu32*)l, 16, 0, 0);
}

__device__ __forceinline__ unsigned short f2bf(float f) {
  union { float f; unsigned int u; } v; v.f = f;
  unsigned int r = v.u + 0x7FFFu + ((v.u >> 16) & 1u);  // RNE
  return (unsigned short)(r >> 16);
}

// ---------------- cast x to bf16 ----------------
__global__ __launch_bounds__(256) void init_cast_kernel(
    const float* __restrict__ x, unsigned short* __restrict__ xb) {
  int t = blockIdx.x * 256 + threadIdx.x;
  float4 v = reinterpret_cast<const float4*>(x)[t];
  ushort4 o;
  o.x = f2bf(v.x); o.y = f2bf(v.y); o.z = f2bf(v.z); o.w = f2bf(v.w);
  reinterpret_cast<ushort4*>(xb)[t] = o;
}

// ---------------- router: gates + top-2 ----------------
#define RT 8
__global__ __launch_bounds__(256) void router_kernel(
    const float* __restrict__ x, const float* __restrict__ Wr1,
    const float* __restrict__ br1, const float* __restrict__ Wr2,
    const float* __restrict__ br2, int* __restrict__ ti,
    float* __restrict__ tw) {
  __shared__ float xs[RT][CDIM];
  __shared__ float hs[RT][CRDIM];
  __shared__ float lg[RT][ENUM];
  const int tid = threadIdx.x;
  const int tok0 = blockIdx.x * RT;
  for (int r = 0; r < RT; ++r) {
    float4 v = reinterpret_cast<const float4*>(x + (size_t)(tok0 + r) * CDIM)[tid];
    *reinterpret_cast<float4*>(&xs[r][tid * 4]) = v;
  }
  __syncthreads();
  float acc[RT];
#pragma unroll
  for (int r = 0; r < RT; ++r) acc[r] = 0.f;
  const int j = tid;
  for (int i = 0; i < CDIM; ++i) {
    float w = Wr1[(size_t)i * CRDIM + j];
#pragma unroll
    for (int r = 0; r < RT; ++r) acc[r] += xs[r][i] * w;
  }
  float b = br1[j];
#pragma unroll
  for (int r = 0; r < RT; ++r) hs[r][j] = fmaxf(acc[r] + b, 0.f);
  __syncthreads();
  if (tid < RT * ENUM) {
    int r = tid >> 3, e = tid & 7;
    float a = 0.f;
    for (int i = 0; i < CRDIM; ++i) a += hs[r][i] * Wr2[(size_t)i * ENUM + e];
    lg[r][e] = a + br2[e];
  }
  __syncthreads();
  if (tid < RT) {
    int r = tid;
    float m = lg[r][0];
#pragma unroll
    for (int e = 1; e < 8; ++e) m = fmaxf(m, lg[r][e]);
    float s = 0.f, g[8];
#pragma unroll
    for (int e = 0; e < 8; ++e) { g[e] = expf(lg[r][e] - m); s += g[e]; }
    float inv = 1.f / s;
    int i0 = 0; float g0 = -1.f;
#pragma unroll
    for (int e = 0; e < 8; ++e) { float ge = g[e] * inv; if (ge > g0) { g0 = ge; i0 = e; } }
    int i1 = 0; float g1 = -2.f;
#pragma unroll
    for (int e = 0; e < 8; ++e) { float ge = g[e] * inv; if (e != i0 && ge > g1) { g1 = ge; i1 = e; } }
    float w0 = 1.f / (1.f + expf((g1 - g0) * 0.5f));
    int n = tok0 + r;
    ti[2 * n] = i0; ti[2 * n + 1] = i1;
    tw[2 * n] = w0; tw[2 * n + 1] = 1.f - w0;
  }
}

// ---------------- per-expert token lists (stable order) + tokslot map ---------
__global__ __launch_bounds__(1024) void build_lists_kernel(
    const int* __restrict__ ti, const float* __restrict__ tw,
    int* __restrict__ cnt, int* __restrict__ list, float* __restrict__ gw,
    int* __restrict__ tokslot) {
  __shared__ int s[NTOK];
  const int e = blockIdx.x, n = threadIdx.x;
  int a = ti[2 * n], b = ti[2 * n + 1];
  float w = (a == e) ? tw[2 * n] : ((b == e) ? tw[2 * n + 1] : 0.f);
  int flag = (a == e || b == e) ? 1 : 0;
  s[n] = flag;
  __syncthreads();
  for (int off = 1; off < NTOK; off <<= 1) {
    int v = (n >= off) ? s[n - off] : 0;
    __syncthreads();
    s[n] += v;
    __syncthreads();
  }
  if (flag) {
    int pos = s[n] - 1;
    list[e * NTOK + pos] = n; gw[e * NTOK + pos] = w;
    int slot = (a == e) ? 0 : 1;
    tokslot[2 * n + slot] = (e << 16) | pos;
  }
  if (n == NTOK - 1) cnt[e] = s[n];
}

// offsets + M-tile table: tbl[0]=ntt; tbl[1+i]=expert; tbl[41+i]=row0
__global__ void offsets_kernel(const int* __restrict__ cnt, int* __restrict__ offs,
                               int* __restrict__ tbl) {
  if (threadIdx.x == 0) {
    int o = 0;
    for (int e = 0; e < 8; ++e) { offs[e] = o; o += cnt[e]; }
    offs[8] = o;
    int k = 0;
    for (int e = 0; e < 9; ++e) {
      int me = (e < 8) ? cnt[e] : NTOK;
      for (int r0 = 0; r0 < me; r0 += 128) { tbl[1 + k] = e; tbl[41 + k] = r0; ++k; }
    }
    tbl[0] = k;
  }
}

// ---- direct-f32-weight MFMA GEMM block ----
// A: bf16 (glds16, 3-deep, swizzled).  B: f32 weights -> reg -> cvt -> LDS
// (2 LDS bufs bridged by 2 register sets => 3-tile load depth, counted vmcnt).
// MODE 0: H[hrow] = silu(Xg @ W1 + b1)            (bf16 store)
// MODE 1: pout[kc][hrow] = H @ W2 (+b2 @ kc==0)   (f32 plain store, split-K=4)
template <int MODE>
__device__ __forceinline__ void gemm_blockd(
    const unsigned short* __restrict__ Abase,
    const float* __restrict__ Wr, const float* __restrict__ Wsh,
    const float* __restrict__ br, const float* __restrict__ bsh,
    const int* __restrict__ cnt, const int* __restrict__ offs,
    const int* __restrict__ list,
    unsigned short* __restrict__ Hout, float* __restrict__ pout,
    int e, int row0, int kc, int nt,
    unsigned short* smA /*3*4096*/, unsigned short* smB /*2*5120*/) {
  constexpr int KD = (MODE == 0) ? CDIM : IDIM;   // A k-stride
  constexpr int ND = (MODE == 0) ? IDIM : CDIM;   // B row length
  constexpr int KCH = 1024;
  constexpr int NT = KCH / 32;                    // 32
  const int me = (e < 8) ? cnt[e] : NTOK;
  const int valid = min(128, me - row0);
  const int n0 = nt * 128;
  const float* Bsrc = (e < 8) ? (Wr + (size_t)e * WSTRIDE) : Wsh;
  const float* bias = (e < 8) ? (br + (size_t)e * ND) : bsh;
  const int hbase = (e < 8) ? offs[e] : 2048;
  const int tid = threadIdx.x;
  const int lane = tid & 63, w = tid >> 6;

  // ---- A staging (glds16): wave w rows [16w,16w+16) and [64+16w,..) ----
  const int rl = lane >> 2, cs = lane & 3;
  const int ra0 = w * 16 + rl, ra1 = 64 + w * 16 + rl;
  const int qa0 = cs ^ ((ra0 >> 1) & 3), qa1 = cs ^ ((ra1 >> 1) & 3);
  const int kbeg = kc * KCH;
  size_t arow0, arow1;
  if (MODE == 0) {
    if (e < 8) {
      arow0 = (size_t)list[e * NTOK + row0 + min(ra0, valid - 1)];
      arow1 = (size_t)list[e * NTOK + row0 + min(ra1, valid - 1)];
    } else { arow0 = (size_t)(row0 + ra0); arow1 = (size_t)(row0 + ra1); }
  } else { arow0 = (size_t)(hbase + row0 + ra0); arow1 = (size_t)(hbase + row0 + ra1); }
  const unsigned short* srcA0 = Abase + arow0 * KD + kbeg + qa0 * 8;
  const unsigned short* srcA1 = Abase + arow1 * KD + kbeg + qa1 * 8;
  const int aO0 = (w * 16) * 32, aO1 = (64 + w * 16) * 32;

  // ---- B staging: thread -> col pair {2c2,2c2+1}, k-run ksg..ksg+7 ----
  const int c2 = tid & 63;
  const int ksg = (tid >> 6) * 8;
  const float* srcB = Bsrc + (size_t)(kbeg + ksg) * ND + n0 + 2 * c2;
  const int bO0 = (2 * c2) * 40 + ksg;       // ushort units, col stride 40 (80 B)
  const int bO1 = (2 * c2 + 1) * 40 + ksg;

  // ---- fragment offsets ----
  const int wr = (w >> 1) * 64, wc = (w & 1) * 64;
  const int lr = lane & 15, q = lane >> 4;
  int offA[4], offB[4];
#pragma unroll
  for (int m = 0; m < 4; ++m) { int R = wr + m * 16 + lr; offA[m] = R * 32 + (q ^ ((R >> 1) & 3)) * 8; }
#pragma unroll
  for (int n = 0; n < 4; ++n) { int R = wc + n * 16 + lr; offB[n] = R * 40 + q * 8; }

  f32x4 acc[4][4];
#pragma unroll
  for (int m = 0; m < 4; ++m)
#pragma unroll
    for (int n = 0; n < 4; ++n) acc[m][n] = (f32x4)0.f;

  unsigned short *ca = smA, *na = smA + 4096, *wa = smA + 8192;
  unsigned short *bc = smB, *bn = smB + 5120;
  float2 rbA[8], rbB[8];

#define BLOAD(T, RB)                                                     \
  {                                                                      \
    const float* bp = srcB + (size_t)(T) * 32 * ND;                      \
    _Pragma("unroll") for (int j = 0; j < 8; ++j)                        \
        RB[j] = *reinterpret_cast<const float2*>(bp + (size_t)j * ND);   \
  }
#define ASTG(T, BA)                                                      \
  {                                                                      \
    glds16(srcA0 + (size_t)(T) * 32, (BA) + aO0);                        \
    glds16(srcA1 + (size_t)(T) * 32, (BA) + aO1);                        \
  }
#define BWRITE(RB, BB)                                                   \
  {                                                                      \
    bf16x8 lo, hi;                                                       \
    _Pragma("unroll") for (int j = 0; j < 8; ++j) {                      \
      lo[j] = (__bf16)RB[j].x; hi[j] = (__bf16)RB[j].y;                  \
    }                                                                    \
    *reinterpret_cast<bf16x8*>((BB) + bO0) = lo;                         \
    *reinterpret_cast<bf16x8*>((BB) + bO1) = hi;                         \
  }
#define MFMAS()                                                          \
  {                                                                      \
    bf16x8 av[4], bv[4];                                                 \
    _Pragma("unroll") for (int m = 0; m < 4; ++m)                        \
        av[m] = *reinterpret_cast<const bf16x8*>(ca + offA[m]);          \
    _Pragma("unroll") for (int n = 0; n < 4; ++n)                        \
        bv[n] = *reinterpret_cast<const bf16x8*>(bc + offB[n]);          \
    _Pragma("unroll") for (int m = 0; m < 4; ++m)                        \
        _Pragma("unroll") for (int n = 0; n < 4; ++n)                    \
            acc[m][n] = __builtin_amdgcn_mfma_f32_16x16x32_bf16(         \
                av[m], bv[n], acc[m][n], 0, 0, 0);                       \
  }

  // prologue: tiles 0,1 in flight; write B(0); publish tile 0
  BLOAD(0, rbA); ASTG(0, ca);
  __builtin_amdgcn_sched_barrier(0);   // group 0 strictly older than group 1
  BLOAD(1, rbB); ASTG(1, na);
  asm volatile("s_waitcnt vmcnt(10)" ::: "memory");  // group 0 done
  __builtin_amdgcn_sched_barrier(0);
  BWRITE(rbA, bc);
  asm volatile("s_waitcnt lgkmcnt(0)" ::: "memory");
  __builtin_amdgcn_s_barrier();
  __builtin_amdgcn_sched_barrier(0);

#define GBODY(T, RL, RW)                                                     \
  {                                                                          \
    if ((T) + 2 < NT) { BLOAD((T) + 2, RL); ASTG((T) + 2, wa); }             \
    MFMAS();                                                                 \
    if ((T) + 1 < NT) {                                                      \
      if ((T) + 2 < NT) {                                                    \
        asm volatile("s_waitcnt vmcnt(10)" ::: "memory");                    \
      } else {                                                               \
        asm volatile("s_waitcnt vmcnt(0)" ::: "memory");                     \
      }                                                                      \
      __builtin_amdgcn_sched_barrier(0);                                     \
      BWRITE(RW, bn);                                                        \
      asm volatile("s_waitcnt lgkmcnt(0)" ::: "memory");                     \
      __builtin_amdgcn_s_barrier();                                          \
      __builtin_amdgcn_sched_barrier(0);                                     \
    }                                                                        \
    { unsigned short* tp = ca; ca = na; na = wa; wa = tp; }                  \
    { unsigned short* tp = bc; bc = bn; bn = tp; }                           \
  }

  for (int t = 0; t < NT; t += 2) {
    GBODY(t, rbA, rbB)
    GBODY(t + 1, rbB, rbA)
  }
#undef GBODY
#undef MFMAS
#undef BWRITE
#undef ASTG
#undef BLOAD

  const int rbase = wr + (q << 2);
#pragma unroll
  for (int n = 0; n < 4; ++n) {
    const int col = n0 + wc + n * 16 + lr;
    const float bval = (MODE == 0 || kc == 0) ? bias[col] : 0.f;
#pragma unroll
    for (int m = 0; m < 4; ++m) {
#pragma unroll
      for (int r = 0; r < 4; ++r) {
        const int i = rbase + m * 16 + r;
        if (i < valid) {
          float v = acc[m][n][r] + bval;
          if (MODE == 0) {
            float sv = v / (1.f + __expf(-v));
            Hout[(size_t)(hbase + row0 + i) * IDIM + col] = f2bf(sv);
          } else {
            pout[((size_t)kc * 3072 + hbase + row0 + i) * CDIM + col] = v;
          }
        }
      }
    }
  }
}

__global__ __launch_bounds__(256) void gemm1d_kernel(
    const unsigned short* __restrict__ xb, const float* __restrict__ We1,
    const float* __restrict__ Ws1, const float* __restrict__ be1,
    const float* __restrict__ bs1, const int* __restrict__ cnt,
    const int* __restrict__ offs, const int* __restrict__ list,
    unsigned short* __restrict__ H, const int* __restrict__ tbl) {
  __shared__ __align__(16) unsigned short smA[3 * 4096];
  __shared__ __align__(16) unsigned short smB[2 * 5120];
  const int y = blockIdx.y;
  if (y >= tbl[0]) return;
  gemm_blockd<0>(xb, We1, Ws1, be1, bs1, cnt, offs, list, H, nullptr,
                 tbl[1 + y], tbl[41 + y], 0, blockIdx.x, smA, smB);
}

__global__ __launch_bounds__(256) void gemm2d_kernel(
    const unsigned short* __restrict__ H, const float* __restrict__ We2,
    const float* __restrict__ Ws2, const float* __restrict__ be2,
    const float* __restrict__ bs2, const int* __restrict__ cnt,
    const int* __restrict__ offs, float* __restrict__ pout,
    const int* __restrict__ tbl) {
  __shared__ __align__(16) unsigned short smA[3 * 4096];
  __shared__ __align__(16) unsigned short smB[2 * 5120];
  const int y = blockIdx.y;
  if (y >= tbl[0]) return;
  const int nt = blockIdx.x & 7, kc = blockIdx.x >> 3;
  gemm_blockd<1>(H, We2, Ws2, be2, bs2, cnt, offs, nullptr, nullptr, pout,
                 tbl[1 + y], tbl[41 + y], kc, nt, smA, smB);
}

// out[tok][c] = sum_kc( pout[kc][shared] + g0*pout[kc][h0] + g1*pout[kc][h1] )
__global__ __launch_bounds__(256) void reduce_kernel(
    const float* __restrict__ pout, const int* __restrict__ tokslot,
    const float* __restrict__ tw, const int* __restrict__ offs,
    float* __restrict__ out) {
  const int tok = blockIdx.x;
  const int c = threadIdx.x * 4;
  const int t0 = tokslot[2 * tok], t1 = tokslot[2 * tok + 1];
  const float g0 = tw[2 * tok], g1 = tw[2 * tok + 1];
  const int r0 = offs[t0 >> 16] + (t0 & 0xffff);
  const int r1 = offs[t1 >> 16] + (t1 & 0xffff);
  const int rs = 2048 + tok;
  float4 acc; acc.x = 0.f; acc.y = 0.f; acc.z = 0.f; acc.w = 0.f;
#pragma unroll
  for (int kc = 0; kc < 4; ++kc) {
    const float* base = pout + (size_t)kc * 3072 * CDIM;
    float4 a = *reinterpret_cast<const float4*>(base + (size_t)rs * CDIM + c);
    float4 b = *reinterpret_cast<const float4*>(base + (size_t)r0 * CDIM + c);
    float4 d = *reinterpret_cast<const float4*>(base + (size_t)r1 * CDIM + c);
    acc.x += a.x + g0 * b.x + g1 * d.x;
    acc.y += a.y + g0 * b.y + g1 * d.y;
    acc.z += a.z + g0 * b.z + g1 * d.z;
    acc.w += a.w + g0 * b.w + g1 * d.w;
  }
  *reinterpret_cast<float4*>(out + (size_t)tok * CDIM + c) = acc;
}

extern "C" void kernel_launch(void* const* d_in, const int* in_sizes, int n_in,
                              void* d_out, int out_size, void* d_ws, size_t ws_size,
                              hipStream_t stream) {
  const float* x = (const float*)d_in[0];
  const float* Wr1 = (const float*)d_in[1];
  const float* br1 = (const float*)d_in[2];
  const float* Wr2 = (const float*)d_in[3];
  const float* br2 = (const float*)d_in[4];
  const float* Ws1 = (const float*)d_in[5];
  const float* bs1 = (const float*)d_in[6];
  const float* Ws2 = (const float*)d_in[7];
  const float* bs2 = (const float*)d_in[8];
  const float* We1 = (const float*)d_in[9];
  const float* be1 = (const float*)d_in[10];
  const float* We2 = (const float*)d_in[11];
  const float* be2 = (const float*)d_in[12];
  float* out = (float*)d_out;

  char* ws = (char*)d_ws;
  unsigned short* xb = (unsigned short*)(ws + 0);            // 2 MB
  int* ti = (int*)(ws + 2097152);
  float* tw = (float*)(ws + 2105344);
  int* cnt = (int*)(ws + 2113536);
  int* offs = (int*)(ws + 2113792);
  int* list = (int*)(ws + 2114048);                          // 32 KB
  float* gw = (float*)(ws + 2146816);                        // 32 KB
  unsigned short* H = (unsigned short*)(ws + 2179584);       // 24 MB -> 27345408
  int* tbl = (int*)(ws + 27345408);                          // 512 B
  int* tokslot = (int*)(ws + 27345920);                      // 8 KB -> 27354112
  float* pout = (float*)(ws + 27354112ull);                  // 48 MB -> 77687808

  init_cast_kernel<<<1024, 256, 0, stream>>>(x, xb);
  router_kernel<<<NTOK / RT, 256, 0, stream>>>(x, Wr1, br1, Wr2, br2, ti, tw);
  build_lists_kernel<<<8, 1024, 0, stream>>>(ti, tw, cnt, list, gw, tokslot);
  offsets_kernel<<<1, 64, 0, stream>>>(cnt, offs, tbl);
  gemm1d_kernel<<<dim3(32, 32), 256, 0, stream>>>(xb, We1, Ws1, be1, bs1, cnt,
                                                  offs, list, H, tbl);
  gemm2d_kernel<<<dim3(32, 32), 256, 0, stream>>>(H, We2, Ws2, be2, bs2, cnt,
                                                  offs, pout, tbl);
  reduce_kernel<<<1024, 256, 0, stream>>>(pout, tokslot, tw, offs, out);
}

// Round 9
// 239.851 us; speedup vs baseline: 2.1258x; 1.2285x over previous
//
#include <hip/hip_runtime.h>

#define NTOK 1024
#define CDIM 1024
#define CRDIM 256
#define ENUM 8
#define IDIM 4096
#define WSTRIDE 4194304ull  // C*I elements per expert weight matrix

typedef __bf16 bf16x8 __attribute__((ext_vector_type(8)));
typedef __bf16 bf16x4 __attribute__((ext_vector_type(4)));
typedef float f32x4 __attribute__((ext_vector_type(4)));

typedef const unsigned int __attribute__((address_space(1))) gu32;
typedef unsigned int __attribute__((address_space(3))) lu32;

__device__ __forceinline__ void glds16(const unsigned short* g, unsigned short* l) {
  __builtin_amdgcn_global_load_lds((gu32*)g, (lu32*)l, 16, 0, 0);
}

__device__ __forceinline__ unsigned short f2bf(float f) {
  union { float f; unsigned int u; } v; v.f = f;
  unsigned int r = v.u + 0x7FFFu + ((v.u >> 16) & 1u);  // RNE
  return (unsigned short)(r >> 16);
}

// ---------------- cast x to bf16 ----------------
__global__ __launch_bounds__(256) void init_cast_kernel(
    const float* __restrict__ x, unsigned short* __restrict__ xb) {
  int t = blockIdx.x * 256 + threadIdx.x;
  float4 v = reinterpret_cast<const float4*>(x)[t];
  ushort4 o;
  o.x = f2bf(v.x); o.y = f2bf(v.y); o.z = f2bf(v.z); o.w = f2bf(v.w);
  reinterpret_cast<ushort4*>(xb)[t] = o;
}

// ---------------- router: gates + top-2 ----------------
#define RT 8
__global__ __launch_bounds__(256) void router_kernel(
    const float* __restrict__ x, const float* __restrict__ Wr1,
    const float* __restrict__ br1, const float* __restrict__ Wr2,
    const float* __restrict__ br2, int* __restrict__ ti,
    float* __restrict__ tw) {
  __shared__ float xs[RT][CDIM];
  __shared__ float hs[RT][CRDIM];
  __shared__ float lg[RT][ENUM];
  const int tid = threadIdx.x;
  const int tok0 = blockIdx.x * RT;
  for (int r = 0; r < RT; ++r) {
    float4 v = reinterpret_cast<const float4*>(x + (size_t)(tok0 + r) * CDIM)[tid];
    *reinterpret_cast<float4*>(&xs[r][tid * 4]) = v;
  }
  __syncthreads();
  float acc[RT];
#pragma unroll
  for (int r = 0; r < RT; ++r) acc[r] = 0.f;
  const int j = tid;
  for (int i = 0; i < CDIM; ++i) {
    float w = Wr1[(size_t)i * CRDIM + j];
#pragma unroll
    for (int r = 0; r < RT; ++r) acc[r] += xs[r][i] * w;
  }
  float b = br1[j];
#pragma unroll
  for (int r = 0; r < RT; ++r) hs[r][j] = fmaxf(acc[r] + b, 0.f);
  __syncthreads();
  if (tid < RT * ENUM) {
    int r = tid >> 3, e = tid & 7;
    float a = 0.f;
    for (int i = 0; i < CRDIM; ++i) a += hs[r][i] * Wr2[(size_t)i * ENUM + e];
    lg[r][e] = a + br2[e];
  }
  __syncthreads();
  if (tid < RT) {
    int r = tid;
    float m = lg[r][0];
#pragma unroll
    for (int e = 1; e < 8; ++e) m = fmaxf(m, lg[r][e]);
    float s = 0.f, g[8];
#pragma unroll
    for (int e = 0; e < 8; ++e) { g[e] = expf(lg[r][e] - m); s += g[e]; }
    float inv = 1.f / s;
    int i0 = 0; float g0 = -1.f;
#pragma unroll
    for (int e = 0; e < 8; ++e) { float ge = g[e] * inv; if (ge > g0) { g0 = ge; i0 = e; } }
    int i1 = 0; float g1 = -2.f;
#pragma unroll
    for (int e = 0; e < 8; ++e) { float ge = g[e] * inv; if (e != i0 && ge > g1) { g1 = ge; i1 = e; } }
    float w0 = 1.f / (1.f + expf((g1 - g0) * 0.5f));
    int n = tok0 + r;
    ti[2 * n] = i0; ti[2 * n + 1] = i1;
    tw[2 * n] = w0; tw[2 * n + 1] = 1.f - w0;
  }
}

// ---------------- per-expert token lists (stable order) + tokslot map ---------
__global__ __launch_bounds__(1024) void build_lists_kernel(
    const int* __restrict__ ti, const float* __restrict__ tw,
    int* __restrict__ cnt, int* __restrict__ list, float* __restrict__ gw,
    int* __restrict__ tokslot) {
  __shared__ int s[NTOK];
  const int e = blockIdx.x, n = threadIdx.x;
  int a = ti[2 * n], b = ti[2 * n + 1];
  float w = (a == e) ? tw[2 * n] : ((b == e) ? tw[2 * n + 1] : 0.f);
  int flag = (a == e || b == e) ? 1 : 0;
  s[n] = flag;
  __syncthreads();
  for (int off = 1; off < NTOK; off <<= 1) {
    int v = (n >= off) ? s[n - off] : 0;
    __syncthreads();
    s[n] += v;
    __syncthreads();
  }
  if (flag) {
    int pos = s[n] - 1;
    list[e * NTOK + pos] = n; gw[e * NTOK + pos] = w;
    int slot = (a == e) ? 0 : 1;
    tokslot[2 * n + slot] = (e << 16) | pos;
  }
  if (n == NTOK - 1) cnt[e] = s[n];
}

// offsets + 256-row M-tile table: tbl[0]=ntt; tbl[1+i]=expert; tbl[41+i]=row0
__global__ void offsets_kernel(const int* __restrict__ cnt, int* __restrict__ offs,
                               int* __restrict__ tbl) {
  if (threadIdx.x == 0) {
    int o = 0;
    for (int e = 0; e < 8; ++e) { offs[e] = o; o += cnt[e]; }
    offs[8] = o;
    int k = 0;
    for (int e = 0; e < 9; ++e) {
      int me = (e < 8) ? cnt[e] : NTOK;
      for (int r0 = 0; r0 < me; r0 += 256) { tbl[1 + k] = e; tbl[41 + k] = r0; ++k; }
    }
    tbl[0] = k;
  }
}

// ---- 512-thread 256x128 GEMM, direct f32 weights, counted-vmcnt pipeline ----
// MODE 0: H[hrow] = silu(Xg @ W1 + b1)            (bf16 store)
// MODE 1: pout[kc][hrow] = H @ W2 (+b2 @ kc==0)   (f32 plain store, split-K=4)
template <int MODE>
__global__ __launch_bounds__(512, 4) void gemm_w(
    const unsigned short* __restrict__ Abase,
    const float* __restrict__ Wr, const float* __restrict__ Wsh,
    const float* __restrict__ br, const float* __restrict__ bsh,
    const int* __restrict__ cnt, const int* __restrict__ offs,
    const int* __restrict__ list,
    unsigned short* __restrict__ Hout, float* __restrict__ pout,
    const int* __restrict__ tbl) {
  __shared__ __align__(16) unsigned short smA[3 * 8192];  // 3 x [256m][32k] bf16
  __shared__ __align__(16) unsigned short smB[2 * 5120];  // 2 x [128n][40] bf16
  const int y = blockIdx.y;
  if (y >= tbl[0]) return;
  const int e = tbl[1 + y], row0 = tbl[41 + y];
  const int nt = (MODE == 0) ? blockIdx.x : (blockIdx.x & 7);
  const int kc = (MODE == 0) ? 0 : (blockIdx.x >> 3);

  constexpr int KD = (MODE == 0) ? CDIM : IDIM;  // A row length
  constexpr int ND = (MODE == 0) ? IDIM : CDIM;  // B row length (f32 [K][N])
  constexpr int NT = 32;                         // K-chunk 1024 / BK 32
  const int me = (e < 8) ? cnt[e] : NTOK;
  const int valid = min(256, me - row0);
  const int n0 = nt * 128;
  const float* Bsrc = (e < 8) ? (Wr + (size_t)e * WSTRIDE) : Wsh;
  const float* bias = (e < 8) ? (br + (size_t)e * ND) : bsh;
  const int hbase = (e < 8) ? offs[e] : 2048;
  const int tid = threadIdx.x;
  const int lane = tid & 63, w = tid >> 6;
  const int kbeg = kc * 1024;

  // ---- A staging (glds16): wave w covers rows [32w,32w+16) and [32w+16,32w+32)
  const int rl = lane >> 2, cs = lane & 3;
  const int r0w = 32 * w + rl;
  const int q0 = cs ^ ((r0w >> 1) & 3);
  const int q1 = cs ^ (((r0w + 16) >> 1) & 3);
  int src_r0, src_r1;
  if (MODE == 0) {
    if (e < 8) {
      src_r0 = list[e * NTOK + row0 + min(r0w, valid - 1)];
      src_r1 = list[e * NTOK + row0 + min(r0w + 16, valid - 1)];
    } else {
      src_r0 = row0 + min(r0w, valid - 1);
      src_r1 = row0 + min(r0w + 16, valid - 1);
    }
  } else {
    src_r0 = hbase + row0 + min(r0w, valid - 1);
    src_r1 = hbase + row0 + min(r0w + 16, valid - 1);
  }
  const unsigned short* srcA0 = Abase + (size_t)src_r0 * KD + kbeg + q0 * 8;
  const unsigned short* srcA1 = Abase + (size_t)src_r1 * KD + kbeg + q1 * 8;
  const int aB0 = (32 * w) * 32;
  const int aB1 = (32 * w + 16) * 32;

  // ---- B staging: thread -> 4 cols {c4..c4+3} at k-pair kp (k=2kp,2kp+1) ----
  const int c4 = (tid & 31) * 4;
  const int kp = tid >> 5;  // 0..15
  const float* srcB = Bsrc + (size_t)(kbeg + 2 * kp) * ND + n0 + c4;

  // ---- fragment offsets ----
  const int wr = (w >> 1) * 64, wc = (w & 1) * 64;
  const int lr = lane & 15, q = lane >> 4;
  int offA[4], offB0[4];
#pragma unroll
  for (int m = 0; m < 4; ++m) {
    int R = wr + m * 16 + lr;
    offA[m] = R * 32 + (q ^ ((R >> 1) & 3)) * 8;
  }
#pragma unroll
  for (int n = 0; n < 4; ++n) {
    int R = wc + n * 16 + lr;
    int u = (R >> 3) & 7;
    offB0[n] = R * 40 + ((2 * q) ^ u) * 4;  // second half: ^4
  }

  f32x4 acc[4][4];
#pragma unroll
  for (int m = 0; m < 4; ++m)
#pragma unroll
    for (int n = 0; n < 4; ++n) acc[m][n] = (f32x4)0.f;

  unsigned short *ca = smA, *na = smA + 8192, *wa = smA + 16384;
  unsigned short *bc = smB, *bn = smB + 5120;
  f32x4 rbA[2], rbB[2];

#define ASTG(T, BA)                                       \
  {                                                       \
    glds16(srcA0 + (size_t)(T) * 32, (BA) + aB0);         \
    glds16(srcA1 + (size_t)(T) * 32, (BA) + aB1);         \
  }
#define BLOAD(T, R)                                       \
  {                                                       \
    const float* bp = srcB + (size_t)(T) * 32 * ND;       \
    R[0] = *reinterpret_cast<const f32x4*>(bp);           \
    R[1] = *reinterpret_cast<const f32x4*>(bp + ND);      \
  }
#define BWRITE(R, BB)                                                          \
  {                                                                            \
    _Pragma("unroll") for (int j = 0; j < 4; ++j) {                            \
      int col = c4 + j;                                                        \
      int kp2 = kp ^ (2 * ((col >> 3) & 7));                                   \
      unsigned int pk =                                                        \
          (unsigned int)__builtin_bit_cast(unsigned short, (__bf16)R[0][j]) |  \
          ((unsigned int)__builtin_bit_cast(unsigned short, (__bf16)R[1][j])   \
           << 16);                                                             \
      *reinterpret_cast<unsigned int*>((BB) + col * 40 + kp2 * 2) = pk;        \
    }                                                                          \
  }
#define MFMAS()                                                                \
  {                                                                            \
    bf16x8 av[4];                                                              \
    _Pragma("unroll") for (int m = 0; m < 4; ++m)                              \
        av[m] = *reinterpret_cast<const bf16x8*>(ca + offA[m]);                \
    _Pragma("unroll") for (int n = 0; n < 4; ++n) {                            \
      bf16x4 lo = *reinterpret_cast<const bf16x4*>(bc + offB0[n]);             \
      bf16x4 hi = *reinterpret_cast<const bf16x4*>(bc + (offB0[n] ^ 4));       \
      bf16x8 bv = __builtin_shufflevector(lo, hi, 0, 1, 2, 3, 4, 5, 6, 7);     \
      _Pragma("unroll") for (int m = 0; m < 4; ++m)                            \
          acc[m][n] = __builtin_amdgcn_mfma_f32_16x16x32_bf16(av[m], bv,       \
                                                              acc[m][n], 0,   \
                                                              0, 0);           \
    }                                                                          \
  }

  // prologue: tiles 0,1 in flight; publish tile 0
  ASTG(0, ca); BLOAD(0, rbA);
  __builtin_amdgcn_sched_barrier(0);
  ASTG(1, na); BLOAD(1, rbB);
  asm volatile("s_waitcnt vmcnt(4)" ::: "memory");  // tile0 A in LDS, B in regs
  __builtin_amdgcn_sched_barrier(0);
  BWRITE(rbA, bc);
  asm volatile("s_waitcnt lgkmcnt(0)" ::: "memory");
  __builtin_amdgcn_s_barrier();
  __builtin_amdgcn_sched_barrier(0);

#define GBODY(T, RL, RW)                                                     \
  {                                                                          \
    if ((T) + 2 < NT) { ASTG((T) + 2, wa); BLOAD((T) + 2, RL); }             \
    MFMAS();                                                                 \
    if ((T) + 1 < NT) {                                                      \
      if ((T) + 2 < NT) {                                                    \
        asm volatile("s_waitcnt vmcnt(4)" ::: "memory");                     \
      } else {                                                               \
        asm volatile("s_waitcnt vmcnt(0)" ::: "memory");                     \
      }                                                                      \
      __builtin_amdgcn_sched_barrier(0);                                     \
      BWRITE(RW, bn);                                                        \
      asm volatile("s_waitcnt lgkmcnt(0)" ::: "memory");                     \
      __builtin_amdgcn_s_barrier();                                          \
      __builtin_amdgcn_sched_barrier(0);                                     \
    }                                                                        \
    { unsigned short* tp = ca; ca = na; na = wa; wa = tp; }                  \
    { unsigned short* tp = bc; bc = bn; bn = tp; }                           \
  }

  for (int t = 0; t < NT; t += 2) {
    GBODY(t, rbA, rbB)
    GBODY(t + 1, rbB, rbA)
  }
#undef GBODY
#undef MFMAS
#undef BWRITE
#undef BLOAD
#undef ASTG

  const int rbase = wr + (q << 2);
#pragma unroll
  for (int n = 0; n < 4; ++n) {
    const int col = n0 + wc + n * 16 + lr;
    const float bval = (MODE == 0 || kc == 0) ? bias[col] : 0.f;
#pragma unroll
    for (int m = 0; m < 4; ++m) {
#pragma unroll
      for (int r = 0; r < 4; ++r) {
        const int i = rbase + m * 16 + r;
        if (i < valid) {
          float v = acc[m][n][r] + bval;
          if (MODE == 0) {
            float sv = v / (1.f + __expf(-v));
            Hout[(size_t)(hbase + row0 + i) * IDIM + col] = f2bf(sv);
          } else {
            pout[((size_t)kc * 3072 + hbase + row0 + i) * CDIM + col] = v;
          }
        }
      }
    }
  }
}

// out[tok][c] = sum_kc( pout[kc][shared] + g0*pout[kc][h0] + g1*pout[kc][h1] )
__global__ __launch_bounds__(256) void reduce_kernel(
    const float* __restrict__ pout, const int* __restrict__ tokslot,
    const float* __restrict__ tw, const int* __restrict__ offs,
    float* __restrict__ out) {
  const int tok = blockIdx.x;
  const int c = threadIdx.x * 4;
  const int t0 = tokslot[2 * tok], t1 = tokslot[2 * tok + 1];
  const float g0 = tw[2 * tok], g1 = tw[2 * tok + 1];
  const int r0 = offs[t0 >> 16] + (t0 & 0xffff);
  const int r1 = offs[t1 >> 16] + (t1 & 0xffff);
  const int rs = 2048 + tok;
  float4 acc; acc.x = 0.f; acc.y = 0.f; acc.z = 0.f; acc.w = 0.f;
#pragma unroll
  for (int kc = 0; kc < 4; ++kc) {
    const float* base = pout + (size_t)kc * 3072 * CDIM;
    float4 a = *reinterpret_cast<const float4*>(base + (size_t)rs * CDIM + c);
    float4 b = *reinterpret_cast<const float4*>(base + (size_t)r0 * CDIM + c);
    float4 d = *reinterpret_cast<const float4*>(base + (size_t)r1 * CDIM + c);
    acc.x += a.x + g0 * b.x + g1 * d.x;
    acc.y += a.y + g0 * b.y + g1 * d.y;
    acc.z += a.z + g0 * b.z + g1 * d.z;
    acc.w += a.w + g0 * b.w + g1 * d.w;
  }
  *reinterpret_cast<float4*>(out + (size_t)tok * CDIM + c) = acc;
}

extern "C" void kernel_launch(void* const* d_in, const int* in_sizes, int n_in,
                              void* d_out, int out_size, void* d_ws, size_t ws_size,
                              hipStream_t stream) {
  const float* x = (const float*)d_in[0];
  const float* Wr1 = (const float*)d_in[1];
  const float* br1 = (const float*)d_in[2];
  const float* Wr2 = (const float*)d_in[3];
  const float* br2 = (const float*)d_in[4];
  const float* Ws1 = (const float*)d_in[5];
  const float* bs1 = (const float*)d_in[6];
  const float* Ws2 = (const float*)d_in[7];
  const float* bs2 = (const float*)d_in[8];
  const float* We1 = (const float*)d_in[9];
  const float* be1 = (const float*)d_in[10];
  const float* We2 = (const float*)d_in[11];
  const float* be2 = (const float*)d_in[12];
  float* out = (float*)d_out;

  char* ws = (char*)d_ws;
  unsigned short* xb = (unsigned short*)(ws + 0);            // 2 MB
  int* ti = (int*)(ws + 2097152);
  float* tw = (float*)(ws + 2105344);
  int* cnt = (int*)(ws + 2113536);
  int* offs = (int*)(ws + 2113792);
  int* list = (int*)(ws + 2114048);                          // 32 KB
  float* gw = (float*)(ws + 2146816);                        // 32 KB
  unsigned short* H = (unsigned short*)(ws + 2179584);       // 24 MB -> 27345408
  int* tbl = (int*)(ws + 27345408);                          // 512 B
  int* tokslot = (int*)(ws + 27345920);                      // 8 KB -> 27354112
  float* pout = (float*)(ws + 27354112ull);                  // 48 MB -> 77687808

  init_cast_kernel<<<1024, 256, 0, stream>>>(x, xb);
  router_kernel<<<NTOK / RT, 256, 0, stream>>>(x, Wr1, br1, Wr2, br2, ti, tw);
  build_lists_kernel<<<8, 1024, 0, stream>>>(ti, tw, cnt, list, gw, tokslot);
  offsets_kernel<<<1, 64, 0, stream>>>(cnt, offs, tbl);
  gemm_w<0><<<dim3(32, 20), 512, 0, stream>>>(xb, We1, Ws1, be1, bs1, cnt, offs,
                                              list, H, nullptr, tbl);
  gemm_w<1><<<dim3(32, 20), 512, 0, stream>>>(H, We2, Ws2, be2, bs2, cnt, offs,
                                              nullptr, nullptr, pout, tbl);
  reduce_kernel<<<1024, 256, 0, stream>>>(pout, tokslot, tw, offs, out);
}